// Round 11
// baseline (260.114 us; speedup 1.0000x reference)
//
#include <hip/hip_runtime.h>
#include <math.h>

// DisplacementTensors: per-edge radial-MLP + segment-sum to nodes + per-node linear map.
// N_NODES=50000, N_EDGES=1600000, DIM_A=DIM_V=32, R0=5, LEAK=0.1
//
// Round 11: r10's MFMA-MLP hit prediction (102us) but occupancy stuck at 37%:
// LDS 40960 x 4 = exactly 160KiB -> only 3 blocks/CU resident. Fix 1: row
// stride 36->34 floats (136B, b64-aligned) -> LDS 38912 -> 4 blocks/CU (50%).
// Fix 2: the serial segmented reduce was 2x redundant (both lane-halves walk
// all 64 slots, each flushes half the sums) -> half-split: half p reduces
// slots [32p,32p+32) accumulating ALL 4 sums for its dim, flushes 4 atomics
// per segment; boundary-spanning segments flushed twice, atomics sum (+40%
// flush atomics, uncontended). Reduce: 64 -> 32 iters, halves its VALU+DS.
//
// d_out layout: A_a [50000*32] floats, then out_v [50000*32*3] floats.
// ws (new path): rec u32[NE*4] | emb16 u32[NN*16] | counts[NN] |
//                offsets[NN+1] | rank[NE] | bsum[256] | bbase[256]

#define NN 50000
#define NE 1600000
#define DA 32
#define PI_R0 0.62831853071795864769f  // pi / 5
#define SCAN_BLOCKS 196                // ceil(NN/256)
#define RSTRIDE 34                     // xrad row stride in floats (136B, b64-aligned, bank-clean)

typedef float v2f __attribute__((ext_vector_type(2)));
typedef short bf16x8 __attribute__((ext_vector_type(8)));   // 8 bf16 = 4 VGPRs
typedef float f32x16 __attribute__((ext_vector_type(16)));  // MFMA C/D

union frag_u { unsigned u[4]; bf16x8 v; };

__device__ __forceinline__ void wsync() {
    // intra-wave LDS handoff: wave is lockstep; drain the DS queue.
    asm volatile("s_waitcnt lgkmcnt(0)" ::: "memory");
}

__device__ __forceinline__ unsigned cvt_pk(float lo, float hi) {
    unsigned r;
    asm("v_cvt_pk_bf16_f32 %0, %1, %2" : "=v"(r) : "v"(lo), "v"(hi));
    return r;   // lo -> low 16, hi -> high 16
}

__device__ __forceinline__ float leaky(float x) {
    return fmaxf(x, 0.0f) + 0.1f * fminf(x, 0.0f);
}

// round-to-nearest-ish bf16 (add half-ulp then truncate)
__device__ __forceinline__ unsigned bf_hi(float x) {
    return (__float_as_uint(x) + 0x8000u) >> 16;
}
__device__ __forceinline__ unsigned bf_pack2(float lo, float hi) {
    return bf_hi(lo) | ((__float_as_uint(hi) + 0x8000u) & 0xffff0000u);
}

// ---------------- CSR build ----------------

__global__ __launch_bounds__(256) void k_hist(const int* __restrict__ src,
                                              int* __restrict__ counts,
                                              int* __restrict__ rank) {
    const int e = blockIdx.x * 256 + threadIdx.x;   // grid exactly NE/256
    rank[e] = atomicAdd(&counts[src[e]], 1);
}

__global__ __launch_bounds__(256) void k_scanA(const int* __restrict__ counts,
                                               int* __restrict__ bsum) {
    __shared__ int red[256];
    const int t = threadIdx.x;
    const int idx = blockIdx.x * 256 + t;
    red[t] = (idx < NN) ? counts[idx] : 0;
    __syncthreads();
    #pragma unroll
    for (int off = 128; off > 0; off >>= 1) {
        if (t < off) red[t] += red[t + off];
        __syncthreads();
    }
    if (t == 0) bsum[blockIdx.x] = red[0];
}

__global__ __launch_bounds__(256) void k_scanB(const int* __restrict__ bsum,
                                               int* __restrict__ bbase) {
    __shared__ int s[256];
    const int t = threadIdx.x;
    const int v = (t < SCAN_BLOCKS) ? bsum[t] : 0;
    s[t] = v;
    __syncthreads();
    #pragma unroll
    for (int off = 1; off < 256; off <<= 1) {
        const int x = s[t] + ((t >= off) ? s[t - off] : 0);
        __syncthreads();
        s[t] = x;
        __syncthreads();
    }
    if (t < SCAN_BLOCKS) bbase[t] = s[t] - v;   // exclusive
}

__global__ __launch_bounds__(256) void k_scanC(const int* __restrict__ counts,
                                               const int* __restrict__ bbase,
                                               int* __restrict__ offsets) {
    __shared__ int s[256];
    const int t = threadIdx.x;
    const int idx = blockIdx.x * 256 + t;
    const int v = (idx < NN) ? counts[idx] : 0;
    s[t] = v;
    __syncthreads();
    #pragma unroll
    for (int off = 1; off < 256; off <<= 1) {
        const int x = s[t] + ((t >= off) ? s[t - off] : 0);
        __syncthreads();
        s[t] = x;
        __syncthreads();
    }
    const int excl = s[t] - v + bbase[blockIdx.x];
    if (idx < NN) offsets[idx] = excl;
    if (idx == NN - 1) offsets[NN] = excl + v;   // == NE
}

// scatter + per-edge precompute: sequential reads, random fire-and-forget writes.
// rec = {dist f32, vx|vy bf16x2, vz bf16, src u16 | dst u16 << 16}
__global__ __launch_bounds__(256) void k_prep(
    const float* __restrict__ r_ij,
    const int*   __restrict__ src,
    const int*   __restrict__ dst,
    const int*   __restrict__ offsets,
    const int*   __restrict__ rank,
    uint4* __restrict__ rec)
{
    const int e = blockIdx.x * 256 + threadIdx.x;   // grid exactly NE/256
    const int s = src[e];
    const int slot = offsets[s] + rank[e];

    const float rx = r_ij[(size_t)e*3 + 0];
    const float ry = r_ij[(size_t)e*3 + 1];
    const float rz = r_ij[(size_t)e*3 + 2];
    const float dist = sqrtf(rx*rx + ry*ry + rz*rz);

    const float nq = 1.4f * dist;
    const float e2 = __expf(2.0f * nq);
    const float sc14 = (nq > 0.0f)
        ? 1.4f * (e2 - 1.0f) * __builtin_amdgcn_rcpf((e2 + 1.0f) * nq)
        : 0.0f;

    uint4 r;
    r.x = __float_as_uint(dist);
    r.y = bf_pack2(rx * sc14, ry * sc14);
    r.z = bf_hi(rz * sc14);
    r.w = (unsigned)s | ((unsigned)dst[e] << 16);   // both < 65536
    rec[slot] = r;
}

// res_emb f32 [NN][32] -> packed bf16 u32 [NN][16]
__global__ __launch_bounds__(256) void k_embcvt(const float* __restrict__ emb,
                                                unsigned* __restrict__ emb16) {
    const int t = blockIdx.x * 256 + threadIdx.x;   // grid exactly NN*16/256 = 3125
    emb16[t] = bf_pack2(emb[2*t], emb[2*t + 1]);
}

// ---------------- phase A: MFMA MLP over CSR windows + segmented flush ----------------
// block = 256 = 4 waves; wave owns 64 consecutive CSR slots (one per lane).
// H^T = W X^T per layer, 4x mfma_f32_32x32x16_bf16 per layer; k-slot labeling
// k(g,j)=4g+(j&3)+8*(j>>2) makes layer L's D regs == layer L+1's B frag.
// Then half-split segmented reduce (32 iters) + atomic flush.

__global__ __launch_bounds__(256, 2) void dt_window(
    const uint4*    __restrict__ rec,
    const unsigned* __restrict__ emb16,
    const float* __restrict__ W1, const float* __restrict__ b1,
    const float* __restrict__ W2, const float* __restrict__ b2,
    const float* __restrict__ W3,
    float* __restrict__ A_a,    // [NN][32]  (accumulates, pre-zeroed)
    float* __restrict__ out_v)  // [NN][32][3] (accumulates raw A_v, pre-zeroed)
{
    // rows are 136B: b64-aligned, banks (34*row + col) % 32 = (2*row + col) % 32
    __shared__ float  xrad[4][64][RSTRIDE];   // [wave][edge][dim(+pad)]: bf16 x pairs, then f32 rad
    __shared__ float4 rvn_lds[4][64];         // [wave][slot] = (vx, vy, vz, bits(node))

    const int tid  = threadIdx.x;
    const int wv   = tid >> 6;
    const int lane = tid & 63;
    const int g    = lane >> 5;          // k-group / lane half
    const int m    = lane & 31;          // row (A) / col (B) within tile
    const int slot = blockIdx.x * 256 + tid;   // grid exactly NE/256

    // ---- W fragments, loaded once: wf[layer][kt], A-slot j holds W[m][k(g,j)+16kt] ----
    frag_u wf1[2], wf2[2], wf3[2];
    #pragma unroll
    for (int kt = 0; kt < 2; ++kt) {
        const float4 a1 = *(const float4*)&W1[m*DA + 16*kt + 4*g];
        const float4 c1 = *(const float4*)&W1[m*DA + 16*kt + 8 + 4*g];
        wf1[kt].u[0] = cvt_pk(a1.x, a1.y); wf1[kt].u[1] = cvt_pk(a1.z, a1.w);
        wf1[kt].u[2] = cvt_pk(c1.x, c1.y); wf1[kt].u[3] = cvt_pk(c1.z, c1.w);
        const float4 a2 = *(const float4*)&W2[m*DA + 16*kt + 4*g];
        const float4 c2 = *(const float4*)&W2[m*DA + 16*kt + 8 + 4*g];
        wf2[kt].u[0] = cvt_pk(a2.x, a2.y); wf2[kt].u[1] = cvt_pk(a2.z, a2.w);
        wf2[kt].u[2] = cvt_pk(c2.x, c2.y); wf2[kt].u[3] = cvt_pk(c2.z, c2.w);
        const float4 a3 = *(const float4*)&W3[m*DA + 16*kt + 4*g];
        const float4 c3 = *(const float4*)&W3[m*DA + 16*kt + 8 + 4*g];
        wf3[kt].u[0] = cvt_pk(a3.x, a3.y); wf3[kt].u[1] = cvt_pk(a3.z, a3.w);
        wf3[kt].u[2] = cvt_pk(c3.x, c3.y); wf3[kt].u[3] = cvt_pk(c3.z, c3.w);
    }

    // bias per D-reg r: dim d(r,g) = (r&3) + 8*(r>>2) + 4g
    const float4 b1q0 = *(const float4*)&b1[4*g];
    const float4 b1q1 = *(const float4*)&b1[8 + 4*g];
    const float4 b1q2 = *(const float4*)&b1[16 + 4*g];
    const float4 b1q3 = *(const float4*)&b1[24 + 4*g];
    const float4 b2q0 = *(const float4*)&b2[4*g];
    const float4 b2q1 = *(const float4*)&b2[8 + 4*g];
    const float4 b2q2 = *(const float4*)&b2[16 + 4*g];
    const float4 b2q3 = *(const float4*)&b2[24 + 4*g];

    // ---- per-edge input: radial encode + bf16 emb gather ----
    const uint4 rc = rec[slot];                // sequential b128
    const float dist = __uint_as_float(rc.x);
    const float vx = __uint_as_float(rc.y << 16);
    const float vy = __uint_as_float(rc.y & 0xffff0000u);
    const float vz = __uint_as_float(rc.z << 16);
    const int  node = (int)(rc.w & 0xffffu);
    const int  dn   = (int)(rc.w >> 16);

    v2f xa[16];
    #pragma unroll
    for (int mm = 0; mm < 8; ++mm) {
        float sph, cph;
        __sincosf(PI_R0 * (float)(mm + 1) * dist, &sph, &cph);
        xa[mm]     = (v2f){cph, cph};
        xa[8 + mm] = (v2f){sph, sph};
    }
    const uint4* ep = (const uint4*)(emb16 + (size_t)dn * 16);
    #pragma unroll
    for (int q = 0; q < 4; ++q) {
        const uint4 u = ep[q];
        xa[q*4 + 0] += (v2f){__uint_as_float(u.x << 16), __uint_as_float(u.x & 0xffff0000u)};
        xa[q*4 + 1] += (v2f){__uint_as_float(u.y << 16), __uint_as_float(u.y & 0xffff0000u)};
        xa[q*4 + 2] += (v2f){__uint_as_float(u.z << 16), __uint_as_float(u.z & 0xffff0000u)};
        xa[q*4 + 3] += (v2f){__uint_as_float(u.w << 16), __uint_as_float(u.w & 0xffff0000u)};
    }

    rvn_lds[wv][lane] = make_float4(vx, vy, vz, __int_as_float(node));

    // pack x to bf16 pairs and stash (8 x b64; rows are 8-aligned, not 16)
    {
        uint2* xr = (uint2*)&xrad[wv][lane][0];
        xr[0] = make_uint2(cvt_pk(xa[0].x,  xa[0].y),  cvt_pk(xa[1].x,  xa[1].y));
        xr[1] = make_uint2(cvt_pk(xa[2].x,  xa[2].y),  cvt_pk(xa[3].x,  xa[3].y));
        xr[2] = make_uint2(cvt_pk(xa[4].x,  xa[4].y),  cvt_pk(xa[5].x,  xa[5].y));
        xr[3] = make_uint2(cvt_pk(xa[6].x,  xa[6].y),  cvt_pk(xa[7].x,  xa[7].y));
        xr[4] = make_uint2(cvt_pk(xa[8].x,  xa[8].y),  cvt_pk(xa[9].x,  xa[9].y));
        xr[5] = make_uint2(cvt_pk(xa[10].x, xa[10].y), cvt_pk(xa[11].x, xa[11].y));
        xr[6] = make_uint2(cvt_pk(xa[12].x, xa[12].y), cvt_pk(xa[13].x, xa[13].y));
        xr[7] = make_uint2(cvt_pk(xa[14].x, xa[14].y), cvt_pk(xa[15].x, xa[15].y));
    }
    wsync();

    // ---- first-layer B fragments: B-slot j of tile t holds x[edge 32t+m][k(g,j)+16kt] ----
    frag_u xf[2][2];
    #pragma unroll
    for (int t = 0; t < 2; ++t) {
        const unsigned* er = (const unsigned*)&xrad[wv][32*t + m][0];
        #pragma unroll
        for (int kt = 0; kt < 2; ++kt) {
            const uint2 qa = *(const uint2*)&er[8*kt + 2*g];       // dims 16kt+4g..+3
            const uint2 qb = *(const uint2*)&er[8*kt + 4 + 2*g];   // dims 16kt+8+4g..+3
            xf[t][kt].u[0] = qa.x; xf[t][kt].u[1] = qa.y;
            xf[t][kt].u[2] = qb.x; xf[t][kt].u[3] = qb.y;
        }
    }

    // ---- layer 1 ----
    f32x16 acc0, acc1;
    acc0[0]=b1q0.x; acc0[1]=b1q0.y; acc0[2]=b1q0.z; acc0[3]=b1q0.w;
    acc0[4]=b1q1.x; acc0[5]=b1q1.y; acc0[6]=b1q1.z; acc0[7]=b1q1.w;
    acc0[8]=b1q2.x; acc0[9]=b1q2.y; acc0[10]=b1q2.z; acc0[11]=b1q2.w;
    acc0[12]=b1q3.x; acc0[13]=b1q3.y; acc0[14]=b1q3.z; acc0[15]=b1q3.w;
    acc1 = acc0;
    acc0 = __builtin_amdgcn_mfma_f32_32x32x16_bf16(wf1[0].v, xf[0][0].v, acc0, 0, 0, 0);
    acc0 = __builtin_amdgcn_mfma_f32_32x32x16_bf16(wf1[1].v, xf[0][1].v, acc0, 0, 0, 0);
    acc1 = __builtin_amdgcn_mfma_f32_32x32x16_bf16(wf1[0].v, xf[1][0].v, acc1, 0, 0, 0);
    acc1 = __builtin_amdgcn_mfma_f32_32x32x16_bf16(wf1[1].v, xf[1][1].v, acc1, 0, 0, 0);

    // leaky + repack: D regs -> next-layer B frags (register-local)
    frag_u hf[2][2];
    #pragma unroll
    for (int t = 0; t < 2; ++t) {
        const f32x16 a = t ? acc1 : acc0;
        float h[16];
        #pragma unroll
        for (int r = 0; r < 16; ++r) h[r] = leaky(a[r]);
        hf[t][0].u[0] = cvt_pk(h[0], h[1]);   hf[t][0].u[1] = cvt_pk(h[2], h[3]);
        hf[t][0].u[2] = cvt_pk(h[4], h[5]);   hf[t][0].u[3] = cvt_pk(h[6], h[7]);
        hf[t][1].u[0] = cvt_pk(h[8], h[9]);   hf[t][1].u[1] = cvt_pk(h[10], h[11]);
        hf[t][1].u[2] = cvt_pk(h[12], h[13]); hf[t][1].u[3] = cvt_pk(h[14], h[15]);
    }

    // ---- layer 2 ----
    f32x16 c0, c1;
    c0[0]=b2q0.x; c0[1]=b2q0.y; c0[2]=b2q0.z; c0[3]=b2q0.w;
    c0[4]=b2q1.x; c0[5]=b2q1.y; c0[6]=b2q1.z; c0[7]=b2q1.w;
    c0[8]=b2q2.x; c0[9]=b2q2.y; c0[10]=b2q2.z; c0[11]=b2q2.w;
    c0[12]=b2q3.x; c0[13]=b2q3.y; c0[14]=b2q3.z; c0[15]=b2q3.w;
    c1 = c0;
    c0 = __builtin_amdgcn_mfma_f32_32x32x16_bf16(wf2[0].v, hf[0][0].v, c0, 0, 0, 0);
    c0 = __builtin_amdgcn_mfma_f32_32x32x16_bf16(wf2[1].v, hf[0][1].v, c0, 0, 0, 0);
    c1 = __builtin_amdgcn_mfma_f32_32x32x16_bf16(wf2[0].v, hf[1][0].v, c1, 0, 0, 0);
    c1 = __builtin_amdgcn_mfma_f32_32x32x16_bf16(wf2[1].v, hf[1][1].v, c1, 0, 0, 0);

    frag_u gf[2][2];
    #pragma unroll
    for (int t = 0; t < 2; ++t) {
        const f32x16 a = t ? c1 : c0;
        float h[16];
        #pragma unroll
        for (int r = 0; r < 16; ++r) h[r] = leaky(a[r]);
        gf[t][0].u[0] = cvt_pk(h[0], h[1]);   gf[t][0].u[1] = cvt_pk(h[2], h[3]);
        gf[t][0].u[2] = cvt_pk(h[4], h[5]);   gf[t][0].u[3] = cvt_pk(h[6], h[7]);
        gf[t][1].u[0] = cvt_pk(h[8], h[9]);   gf[t][1].u[1] = cvt_pk(h[10], h[11]);
        gf[t][1].u[2] = cvt_pk(h[12], h[13]); gf[t][1].u[3] = cvt_pk(h[14], h[15]);
    }

    // ---- layer 3 (no bias, no activation) ----
    f32x16 r0 = {}, r1 = {};
    r0 = __builtin_amdgcn_mfma_f32_32x32x16_bf16(wf3[0].v, gf[0][0].v, r0, 0, 0, 0);
    r0 = __builtin_amdgcn_mfma_f32_32x32x16_bf16(wf3[1].v, gf[0][1].v, r0, 0, 0, 0);
    r1 = __builtin_amdgcn_mfma_f32_32x32x16_bf16(wf3[0].v, gf[1][0].v, r1, 0, 0, 0);
    r1 = __builtin_amdgcn_mfma_f32_32x32x16_bf16(wf3[1].v, gf[1][1].v, r1, 0, 0, 0);

    // ---- write rad back: lane holds edge 32t+m, dim quads {4g, 8+4g, 16+4g, 24+4g} (b64 stores) ----
    #pragma unroll
    for (int t = 0; t < 2; ++t) {
        const f32x16 a = t ? r1 : r0;
        float* rr = &xrad[wv][32*t + m][0];
        *(float2*)&rr[4*g]          = make_float2(a[0],  a[1]);
        *(float2*)&rr[4*g + 2]      = make_float2(a[2],  a[3]);
        *(float2*)&rr[8 + 4*g]      = make_float2(a[4],  a[5]);
        *(float2*)&rr[8 + 4*g + 2]  = make_float2(a[6],  a[7]);
        *(float2*)&rr[16 + 4*g]     = make_float2(a[8],  a[9]);
        *(float2*)&rr[16 + 4*g + 2] = make_float2(a[10], a[11]);
        *(float2*)&rr[24 + 4*g]     = make_float2(a[12], a[13]);
        *(float2*)&rr[24 + 4*g + 2] = make_float2(a[14], a[15]);
    }
    wsync();

    // ---- half-split segmented reduce: half p covers slots [32p, 32p+32) ----
    // Every lane accumulates ALL 4 sums for dim i over its half; flushes 4
    // atomics per segment. Boundary-spanning segments flush twice (atomics sum).
    const int p = lane >> 5;
    const int i = lane & 31;
    const int base = p << 5;

    float accA = 0.0f, a0 = 0.0f, a1 = 0.0f, a2 = 0.0f;
    int cur = __float_as_int(rvn_lds[wv][base].w);

    #pragma unroll 4
    for (int l = 0; l < 32; ++l) {
        const float4 rvn = rvn_lds[wv][base + l];   // uniform-per-half b128 broadcast
        const int nd = __float_as_int(rvn.w);
        const float rd = xrad[wv][base + l][i];     // banks (2(base+l)+i)%32: 2-way across halves
        if (nd != cur) {                            // uniform per half-wave
            atomicAdd(&A_a[cur*DA + i], accA);
            atomicAdd(&out_v[(cur*DA + i)*3 + 0], a0);
            atomicAdd(&out_v[(cur*DA + i)*3 + 1], a1);
            atomicAdd(&out_v[(cur*DA + i)*3 + 2], a2);
            accA = a0 = a1 = a2 = 0.0f;
            cur = nd;
        }
        accA += rd;
        a0 += rd * rvn.x;
        a1 += rd * rvn.y;
        a2 += rd * rvn.z;
    }
    atomicAdd(&A_a[cur*DA + i], accA);
    atomicAdd(&out_v[(cur*DA + i)*3 + 0], a0);
    atomicAdd(&out_v[(cur*DA + i)*3 + 1], a1);
    atomicAdd(&out_v[(cur*DA + i)*3 + 2], a2);
}

// ---------------- phase B: out_v[n][v][d] = sum_a Wv[v][a] * A_v[n][a][d], in place ----------------

__global__ __launch_bounds__(256) void dt_node(
    const float* __restrict__ Wv,
    float* Av_out)   // aliased read+write, deliberately NOT restrict
{
    __shared__ float sWv[DA*DA];
    for (int i = threadIdx.x; i < DA*DA; i += 256) sWv[i] = Wv[i];
    __syncthreads();

    const int t = blockIdx.x * 256 + threadIdx.x;   // grid exactly NN*32/256
    const int n = t >> 5;
    const int v = t & 31;

    const float* av = Av_out + (size_t)n * (DA*3);
    float o0 = 0.0f, o1 = 0.0f, o2 = 0.0f;
    #pragma unroll
    for (int a = 0; a < DA; ++a) {
        const float w = sWv[v*DA + a];
        o0 += w * av[a*3 + 0];
        o1 += w * av[a*3 + 1];
        o2 += w * av[a*3 + 2];
    }
    __syncthreads();   // all loads of this block's nodes complete before any store
    float* o = Av_out + (size_t)n * (DA*3) + v*3;
    o[0] = o0; o[1] = o1; o[2] = o2;
}

// ---------------- legacy path (used only if ws too small for the new path) ----------------

__global__ __launch_bounds__(256) void k_scan_legacy(const int* __restrict__ counts,
                                                     int* __restrict__ offsets) {
    __shared__ int part[256];
    const int CH = (NN + 255) / 256;
    const int t = threadIdx.x;
    const int base = t * CH;
    int s = 0;
    for (int k = 0; k < CH; ++k) { const int idx = base + k; if (idx < NN) s += counts[idx]; }
    part[t] = s;
    __syncthreads();
    if (t == 0) {
        int run = 0;
        for (int k = 0; k < 256; ++k) { const int v = part[k]; part[k] = run; run += v; }
    }
    __syncthreads();
    int run = part[t];
    for (int k = 0; k < CH; ++k) {
        const int idx = base + k;
        if (idx < NN) { offsets[idx] = run; run += counts[idx]; }
    }
    if (t == 255) offsets[NN] = run;
}

__global__ __launch_bounds__(256) void k_scatter_legacy(const int* __restrict__ src,
                                                        const int* __restrict__ offsets,
                                                        const int* __restrict__ rank,
                                                        int* __restrict__ edge_ids) {
    const int e = blockIdx.x * 256 + threadIdx.x;
    edge_ids[offsets[src[e]] + rank[e]] = e;
}

__global__ __launch_bounds__(256, 2) void dt_window_legacy(
    const float* __restrict__ r_ij,
    const float* __restrict__ res_emb,
    const int*   __restrict__ src,
    const int*   __restrict__ dst,
    const int*   __restrict__ edge_ids,
    const float* __restrict__ W1, const float* __restrict__ b1,
    const float* __restrict__ W2, const float* __restrict__ b2,
    const float* __restrict__ W3,
    float* __restrict__ A_a,
    float* __restrict__ out_v)
{
    __shared__ float  rad_lds[4][32][36];
    __shared__ float4 rvn_lds[4][64];

    const int tid  = threadIdx.x;
    const int wv   = tid >> 6;
    const int lane = tid & 63;
    const int slot = blockIdx.x * 256 + tid;

    const int eid  = edge_ids[slot];
    const int node = src[eid];

    const float rx = r_ij[(size_t)eid*3 + 0];
    const float ry = r_ij[(size_t)eid*3 + 1];
    const float rz = r_ij[(size_t)eid*3 + 2];
    const float dist = sqrtf(rx*rx + ry*ry + rz*rz);

    float xa[DA], xb[DA];
    #pragma unroll
    for (int mm = 0; mm < 8; ++mm) {
        float sph, cph;
        __sincosf(PI_R0 * (float)(mm + 1) * dist, &sph, &cph);
        xa[2*mm] = cph; xa[2*mm+1] = cph;
        xa[16+2*mm] = sph; xa[16+2*mm+1] = sph;
    }
    const float4* er = (const float4*)(res_emb + (size_t)dst[eid] * DA);
    #pragma unroll
    for (int q = 0; q < 8; ++q) {
        const float4 v = er[q];
        xa[q*4+0] += v.x; xa[q*4+1] += v.y; xa[q*4+2] += v.z; xa[q*4+3] += v.w;
    }
    #pragma unroll
    for (int i = 0; i < DA; ++i) {
        float acc = b1[i];
        #pragma unroll
        for (int j = 0; j < DA; ++j) acc += W1[i*DA + j] * xa[j];
        xb[i] = (acc >= 0.0f) ? acc : 0.1f * acc;
    }
    #pragma unroll
    for (int i = 0; i < DA; ++i) {
        float acc = b2[i];
        #pragma unroll
        for (int j = 0; j < DA; ++j) acc += W2[i*DA + j] * xb[j];
        xa[i] = (acc >= 0.0f) ? acc : 0.1f * acc;
    }
    #pragma unroll
    for (int i = 0; i < DA; ++i) {
        float acc = 0.0f;
        #pragma unroll
        for (int j = 0; j < DA; ++j) acc += W3[i*DA + j] * xa[j];
        xb[i] = acc;
    }

    const float qx = rx*1.4f, qy = ry*1.4f, qz = rz*1.4f;
    const float nq = sqrtf(qx*qx + qy*qy + qz*qz);
    const float e2 = __expf(2.0f * nq);
    const float sc = (nq > 0.0f)
        ? (e2 - 1.0f) * __builtin_amdgcn_rcpf((e2 + 1.0f) * nq)
        : 0.0f;

    rvn_lds[wv][lane] = make_float4(qx*sc, qy*sc, qz*sc, __int_as_float(node));

    const int p = lane >> 5;
    const int i = lane & 31;

    if (lane < 32) {
        float* rrow = rad_lds[wv][lane];
        #pragma unroll
        for (int q = 0; q < 8; ++q)
            *(float4*)&rrow[q*4] = make_float4(xb[q*4+0], xb[q*4+1], xb[q*4+2], xb[q*4+3]);
    }
    wsync();

    float accA = 0.0f, a0 = 0.0f, a1 = 0.0f, a2 = 0.0f;
    int cur = __float_as_int(rvn_lds[wv][0].w);

    #pragma unroll 4
    for (int l = 0; l < 32; ++l) {
        const float4 rvn = rvn_lds[wv][l];
        const int nd = __float_as_int(rvn.w);
        const float rd = rad_lds[wv][l][i];
        if (nd != cur) {
            if (p == 0) {
                atomicAdd(&A_a[cur*DA + i], accA);
                atomicAdd(&out_v[(cur*DA + i)*3 + 0], a0);
            } else {
                atomicAdd(&out_v[(cur*DA + i)*3 + 1], a1);
                atomicAdd(&out_v[(cur*DA + i)*3 + 2], a2);
            }
            accA = a0 = a1 = a2 = 0.0f;
            cur = nd;
        }
        accA += rd; a0 += rd*rvn.x; a1 += rd*rvn.y; a2 += rd*rvn.z;
    }
    wsync();
    if (lane >= 32) {
        float* rrow = rad_lds[wv][lane - 32];
        #pragma unroll
        for (int q = 0; q < 8; ++q)
            *(float4*)&rrow[q*4] = make_float4(xb[q*4+0], xb[q*4+1], xb[q*4+2], xb[q*4+3]);
    }
    wsync();
    #pragma unroll 4
    for (int l = 32; l < 64; ++l) {
        const float4 rvn = rvn_lds[wv][l];
        const int nd = __float_as_int(rvn.w);
        const float rd = rad_lds[wv][l - 32][i];
        if (nd != cur) {
            if (p == 0) {
                atomicAdd(&A_a[cur*DA + i], accA);
                atomicAdd(&out_v[(cur*DA + i)*3 + 0], a0);
            } else {
                atomicAdd(&out_v[(cur*DA + i)*3 + 1], a1);
                atomicAdd(&out_v[(cur*DA + i)*3 + 2], a2);
            }
            accA = a0 = a1 = a2 = 0.0f;
            cur = nd;
        }
        accA += rd; a0 += rd*rvn.x; a1 += rd*rvn.y; a2 += rd*rvn.z;
    }
    if (p == 0) {
        atomicAdd(&A_a[cur*DA + i], accA);
        atomicAdd(&out_v[(cur*DA + i)*3 + 0], a0);
    } else {
        atomicAdd(&out_v[(cur*DA + i)*3 + 1], a1);
        atomicAdd(&out_v[(cur*DA + i)*3 + 2], a2);
    }
}

// ---------------- launch ----------------

extern "C" void kernel_launch(void* const* d_in, const int* in_sizes, int n_in,
                              void* d_out, int out_size, void* d_ws, size_t ws_size,
                              hipStream_t stream) {
    const float* r_ij    = (const float*)d_in[0];
    const float* res_emb = (const float*)d_in[1];
    const int*   src     = (const int*)d_in[2];
    const int*   dst     = (const int*)d_in[3];
    const float* W1      = (const float*)d_in[4];
    const float* b1      = (const float*)d_in[5];
    const float* W2      = (const float*)d_in[6];
    const float* b2      = (const float*)d_in[7];
    const float* W3      = (const float*)d_in[8];
    const float* Wv      = (const float*)d_in[9];

    float* A_a   = (float*)d_out;                    // [NN][32]
    float* out_v = (float*)d_out + (size_t)NN * DA;  // [NN][32][3]

    const size_t need_new = ((size_t)NE*4 + (size_t)NN*16 + NN + NN + 1 + NE + 256 + 256) * sizeof(int);
    const size_t need_leg = ((size_t)NN + NN + 1 + NE + NE) * sizeof(int);

    // output is accumulated into -> must be zeroed every call
    hipMemsetAsync(d_out, 0, (size_t)out_size * sizeof(float), stream);

    if (ws_size >= need_new) {
        uint4*    rec     = (uint4*)d_ws;
        unsigned* emb16   = (unsigned*)(rec + NE);
        int*      counts  = (int*)(emb16 + (size_t)NN*16);
        int*      offsets = counts + NN;
        int*      rank    = offsets + NN + 1;
        int*      bsum    = rank + NE;
        int*      bbase   = bsum + 256;

        hipMemsetAsync(counts, 0, (size_t)NN * sizeof(int), stream);
        k_hist  <<<NE / 256, 256, 0, stream>>>(src, counts, rank);
        k_scanA <<<SCAN_BLOCKS, 256, 0, stream>>>(counts, bsum);
        k_scanB <<<1, 256, 0, stream>>>(bsum, bbase);
        k_scanC <<<SCAN_BLOCKS, 256, 0, stream>>>(counts, bbase, offsets);
        k_embcvt<<<(NN*16) / 256, 256, 0, stream>>>(res_emb, emb16);
        k_prep  <<<NE / 256, 256, 0, stream>>>(r_ij, src, dst, offsets, rank, rec);
        dt_window<<<NE / 256, 256, 0, stream>>>(rec, emb16,
                                                W1, b1, W2, b2, W3, A_a, out_v);
        dt_node <<<(NN * DA) / 256, 256, 0, stream>>>(Wv, out_v);
    } else if (ws_size >= need_leg) {
        int* counts   = (int*)d_ws;
        int* offsets  = counts + NN;
        int* rank     = offsets + NN + 1;
        int* edge_ids = rank + NE;

        hipMemsetAsync(counts, 0, (size_t)NN * sizeof(int), stream);
        k_hist          <<<NE / 256, 256, 0, stream>>>(src, counts, rank);
        k_scan_legacy   <<<1, 256, 0, stream>>>(counts, offsets);
        k_scatter_legacy<<<NE / 256, 256, 0, stream>>>(src, offsets, rank, edge_ids);
        dt_window_legacy<<<NE / 256, 256, 0, stream>>>(r_ij, res_emb, src, dst, edge_ids,
                                                       W1, b1, W2, b2, W3, A_a, out_v);
        dt_node         <<<(NN * DA) / 256, 256, 0, stream>>>(Wv, out_v);
    }
}

// Round 12
// 236.538 us; speedup vs baseline: 1.0997x; 1.0997x over previous
//
#include <hip/hip_runtime.h>
#include <math.h>

// DisplacementTensors: per-edge radial-MLP + segment-sum to nodes + per-node linear map.
// N_NODES=50000, N_EDGES=1600000, DIM_A=DIM_V=32, R0=5, LEAK=0.1
//
// Round 12: r11 regressed (+12us): half-split reduce raised flush atomics
// +33% (WRITE 92.8->123.9MB) -- dt_window is atomic-write sensitive; and LDS
// shrink didn't add a 4th block (occupancy pinned ~3 blocks). Fixes:
//  - dt_window: r10 flush scheme (2 atomics/seg/lane-half) + each wave owns
//    128 contiguous slots as 2 batches with PERSISTENT cur/accumulators
//    (fewer inter-window boundary flushes; W-frag prologue amortized 2x).
//  - chain: k_hist's 1.6M returning atomics at 32-way contention -> 4-way
//    sub-binned hist (key = src*4 + (e&3), 200K bins, ~8-way contention);
//    scan over 200K bins; node slots stay contiguous (adjacent bins), edge
//    order within node permutes (harmless).
//
// d_out layout: A_a [50000*32] floats, then out_v [50000*32*3] floats.
// ws (new path, ~37MB): rec u32[NE*4] | emb16 u32[NN*16] | counts[NB] |
//                       offsets[NB+1] | rank[NE] | bsum[1024] | bbase[1024]

#define NN 50000
#define NE 1600000
#define DA 32
#define NB (NN*4)                      // sub-binned histogram bins
#define PI_R0 0.62831853071795864769f  // pi / 5
#define SCANB_BLOCKS 782               // ceil(NB/256)
#define RSTRIDE 34                     // xrad row stride in floats (136B, b64-aligned)

typedef float v2f __attribute__((ext_vector_type(2)));
typedef short bf16x8 __attribute__((ext_vector_type(8)));   // 8 bf16 = 4 VGPRs
typedef float f32x16 __attribute__((ext_vector_type(16)));  // MFMA C/D

union frag_u { unsigned u[4]; bf16x8 v; };

__device__ __forceinline__ void wsync() {
    // intra-wave LDS handoff: wave is lockstep; drain the DS queue.
    asm volatile("s_waitcnt lgkmcnt(0)" ::: "memory");
}

__device__ __forceinline__ unsigned cvt_pk(float lo, float hi) {
    unsigned r;
    asm("v_cvt_pk_bf16_f32 %0, %1, %2" : "=v"(r) : "v"(lo), "v"(hi));
    return r;   // lo -> low 16, hi -> high 16
}

__device__ __forceinline__ float leaky(float x) {
    return fmaxf(x, 0.0f) + 0.1f * fminf(x, 0.0f);
}

// round-to-nearest-ish bf16 (add half-ulp then truncate)
__device__ __forceinline__ unsigned bf_hi(float x) {
    return (__float_as_uint(x) + 0x8000u) >> 16;
}
__device__ __forceinline__ unsigned bf_pack2(float lo, float hi) {
    return bf_hi(lo) | ((__float_as_uint(hi) + 0x8000u) & 0xffff0000u);
}

// ---------------- CSR build (4-way sub-binned) ----------------

__global__ __launch_bounds__(256) void k_hist(const int* __restrict__ src,
                                              int* __restrict__ counts,
                                              int* __restrict__ rank) {
    const int e = blockIdx.x * 256 + threadIdx.x;   // grid exactly NE/256
    const int key = (src[e] << 2) | (e & 3);        // ~8 edges/bin -> low contention
    rank[e] = atomicAdd(&counts[key], 1);
}

__global__ __launch_bounds__(256) void k_scanA(const int* __restrict__ counts,
                                               int* __restrict__ bsum) {
    __shared__ int red[256];
    const int t = threadIdx.x;
    const int idx = blockIdx.x * 256 + t;
    red[t] = (idx < NB) ? counts[idx] : 0;
    __syncthreads();
    #pragma unroll
    for (int off = 128; off > 0; off >>= 1) {
        if (t < off) red[t] += red[t + off];
        __syncthreads();
    }
    if (t == 0) bsum[blockIdx.x] = red[0];
}

__global__ __launch_bounds__(1024) void k_scanB(const int* __restrict__ bsum,
                                                int* __restrict__ bbase) {
    __shared__ int s[1024];
    const int t = threadIdx.x;
    const int v = (t < SCANB_BLOCKS) ? bsum[t] : 0;
    s[t] = v;
    __syncthreads();
    #pragma unroll
    for (int off = 1; off < 1024; off <<= 1) {
        const int x = s[t] + ((t >= off) ? s[t - off] : 0);
        __syncthreads();
        s[t] = x;
        __syncthreads();
    }
    if (t < SCANB_BLOCKS) bbase[t] = s[t] - v;   // exclusive
}

__global__ __launch_bounds__(256) void k_scanC(const int* __restrict__ counts,
                                               const int* __restrict__ bbase,
                                               int* __restrict__ offsets) {
    __shared__ int s[256];
    const int t = threadIdx.x;
    const int idx = blockIdx.x * 256 + t;
    const int v = (idx < NB) ? counts[idx] : 0;
    s[t] = v;
    __syncthreads();
    #pragma unroll
    for (int off = 1; off < 256; off <<= 1) {
        const int x = s[t] + ((t >= off) ? s[t - off] : 0);
        __syncthreads();
        s[t] = x;
        __syncthreads();
    }
    const int excl = s[t] - v + bbase[blockIdx.x];
    if (idx < NB) offsets[idx] = excl;
    if (idx == NB - 1) offsets[NB] = excl + v;   // == NE
}

// scatter + per-edge precompute: sequential reads, random fire-and-forget writes.
// rec = {dist f32, vx|vy bf16x2, vz bf16, src u16 | dst u16 << 16}
__global__ __launch_bounds__(256) void k_prep(
    const float* __restrict__ r_ij,
    const int*   __restrict__ src,
    const int*   __restrict__ dst,
    const int*   __restrict__ offsets,
    const int*   __restrict__ rank,
    uint4* __restrict__ rec)
{
    const int e = blockIdx.x * 256 + threadIdx.x;   // grid exactly NE/256
    const int s = src[e];
    const int slot = offsets[(s << 2) | (e & 3)] + rank[e];

    const float rx = r_ij[(size_t)e*3 + 0];
    const float ry = r_ij[(size_t)e*3 + 1];
    const float rz = r_ij[(size_t)e*3 + 2];
    const float dist = sqrtf(rx*rx + ry*ry + rz*rz);

    const float nq = 1.4f * dist;
    const float e2 = __expf(2.0f * nq);
    const float sc14 = (nq > 0.0f)
        ? 1.4f * (e2 - 1.0f) * __builtin_amdgcn_rcpf((e2 + 1.0f) * nq)
        : 0.0f;

    uint4 r;
    r.x = __float_as_uint(dist);
    r.y = bf_pack2(rx * sc14, ry * sc14);
    r.z = bf_hi(rz * sc14);
    r.w = (unsigned)s | ((unsigned)dst[e] << 16);   // both < 65536
    rec[slot] = r;
}

// res_emb f32 [NN][32] -> packed bf16 u32 [NN][16]
__global__ __launch_bounds__(256) void k_embcvt(const float* __restrict__ emb,
                                                unsigned* __restrict__ emb16) {
    const int t = blockIdx.x * 256 + threadIdx.x;   // grid exactly NN*16/256 = 3125
    emb16[t] = bf_pack2(emb[2*t], emb[2*t + 1]);
}

// ---------------- phase A: MFMA MLP over CSR windows + segmented flush ----------------
// block = 256 = 4 waves; wave owns 128 contiguous CSR slots, processed as
// 2 batches of 64 (one slot per lane per batch). Per batch: 12x
// mfma_f32_32x32x16_bf16 (k-slot labeling k(g,j)=4g+(j&3)+8*(j>>2) chains
// layer L's D regs directly into layer L+1's B frag), then a serial
// segmented reduce with cur/accumulators PERSISTENT across batches.

__global__ __launch_bounds__(256, 2) void dt_window(
    const uint4*    __restrict__ rec,
    const unsigned* __restrict__ emb16,
    const float* __restrict__ W1, const float* __restrict__ b1,
    const float* __restrict__ W2, const float* __restrict__ b2,
    const float* __restrict__ W3,
    float* __restrict__ A_a,    // [NN][32]  (accumulates, pre-zeroed)
    float* __restrict__ out_v)  // [NN][32][3] (accumulates raw A_v, pre-zeroed)
{
    // rows are 136B: b64-aligned; banks (34*row + col) % 32 = (2*row + col) % 32
    __shared__ float  xrad[4][64][RSTRIDE];   // [wave][edge][dim(+pad)]
    __shared__ float4 rvn_lds[4][64];         // [wave][slot] = (vx, vy, vz, bits(node))

    const int tid   = threadIdx.x;
    const int wv    = tid >> 6;
    const int lane  = tid & 63;
    const int g     = lane >> 5;          // k-group / lane half
    const int m     = lane & 31;          // row (A) / col (B) within tile
    const int wbase = blockIdx.x * 512 + wv * 128;   // grid exactly NE/512

    // ---- W fragments, loaded once: wf[layer][kt], A-slot j holds W[m][k(g,j)+16kt] ----
    frag_u wf1[2], wf2[2], wf3[2];
    #pragma unroll
    for (int kt = 0; kt < 2; ++kt) {
        const float4 a1 = *(const float4*)&W1[m*DA + 16*kt + 4*g];
        const float4 c1 = *(const float4*)&W1[m*DA + 16*kt + 8 + 4*g];
        wf1[kt].u[0] = cvt_pk(a1.x, a1.y); wf1[kt].u[1] = cvt_pk(a1.z, a1.w);
        wf1[kt].u[2] = cvt_pk(c1.x, c1.y); wf1[kt].u[3] = cvt_pk(c1.z, c1.w);
        const float4 a2 = *(const float4*)&W2[m*DA + 16*kt + 4*g];
        const float4 c2 = *(const float4*)&W2[m*DA + 16*kt + 8 + 4*g];
        wf2[kt].u[0] = cvt_pk(a2.x, a2.y); wf2[kt].u[1] = cvt_pk(a2.z, a2.w);
        wf2[kt].u[2] = cvt_pk(c2.x, c2.y); wf2[kt].u[3] = cvt_pk(c2.z, c2.w);
        const float4 a3 = *(const float4*)&W3[m*DA + 16*kt + 4*g];
        const float4 c3 = *(const float4*)&W3[m*DA + 16*kt + 8 + 4*g];
        wf3[kt].u[0] = cvt_pk(a3.x, a3.y); wf3[kt].u[1] = cvt_pk(a3.z, a3.w);
        wf3[kt].u[2] = cvt_pk(c3.x, c3.y); wf3[kt].u[3] = cvt_pk(c3.z, c3.w);
    }

    // bias per D-reg r: dim d(r,g) = (r&3) + 8*(r>>2) + 4g
    const float4 b1q0 = *(const float4*)&b1[4*g];
    const float4 b1q1 = *(const float4*)&b1[8 + 4*g];
    const float4 b1q2 = *(const float4*)&b1[16 + 4*g];
    const float4 b1q3 = *(const float4*)&b1[24 + 4*g];
    const float4 b2q0 = *(const float4*)&b2[4*g];
    const float4 b2q1 = *(const float4*)&b2[8 + 4*g];
    const float4 b2q2 = *(const float4*)&b2[16 + 4*g];
    const float4 b2q3 = *(const float4*)&b2[24 + 4*g];

    const int p = g;
    const int i = m;
    float accA = 0.0f, a0 = 0.0f, a1 = 0.0f, a2 = 0.0f;
    int cur = -1;   // sentinel; node ids >= 0

    #pragma unroll
    for (int b = 0; b < 2; ++b) {
        const int slot = wbase + b*64 + lane;

        // ---- per-edge input: radial encode + bf16 emb gather ----
        const uint4 rc = rec[slot];                // sequential b128
        const float dist = __uint_as_float(rc.x);
        const float vx = __uint_as_float(rc.y << 16);
        const float vy = __uint_as_float(rc.y & 0xffff0000u);
        const float vz = __uint_as_float(rc.z << 16);
        const int  node = (int)(rc.w & 0xffffu);
        const int  dn   = (int)(rc.w >> 16);

        v2f xa[16];
        #pragma unroll
        for (int mm = 0; mm < 8; ++mm) {
            float sph, cph;
            __sincosf(PI_R0 * (float)(mm + 1) * dist, &sph, &cph);
            xa[mm]     = (v2f){cph, cph};
            xa[8 + mm] = (v2f){sph, sph};
        }
        const uint4* ep = (const uint4*)(emb16 + (size_t)dn * 16);
        #pragma unroll
        for (int q = 0; q < 4; ++q) {
            const uint4 u = ep[q];
            xa[q*4 + 0] += (v2f){__uint_as_float(u.x << 16), __uint_as_float(u.x & 0xffff0000u)};
            xa[q*4 + 1] += (v2f){__uint_as_float(u.y << 16), __uint_as_float(u.y & 0xffff0000u)};
            xa[q*4 + 2] += (v2f){__uint_as_float(u.z << 16), __uint_as_float(u.z & 0xffff0000u)};
            xa[q*4 + 3] += (v2f){__uint_as_float(u.w << 16), __uint_as_float(u.w & 0xffff0000u)};
        }

        rvn_lds[wv][lane] = make_float4(vx, vy, vz, __int_as_float(node));

        // pack x to bf16 pairs and stash (8 x b64)
        {
            uint2* xr = (uint2*)&xrad[wv][lane][0];
            xr[0] = make_uint2(cvt_pk(xa[0].x,  xa[0].y),  cvt_pk(xa[1].x,  xa[1].y));
            xr[1] = make_uint2(cvt_pk(xa[2].x,  xa[2].y),  cvt_pk(xa[3].x,  xa[3].y));
            xr[2] = make_uint2(cvt_pk(xa[4].x,  xa[4].y),  cvt_pk(xa[5].x,  xa[5].y));
            xr[3] = make_uint2(cvt_pk(xa[6].x,  xa[6].y),  cvt_pk(xa[7].x,  xa[7].y));
            xr[4] = make_uint2(cvt_pk(xa[8].x,  xa[8].y),  cvt_pk(xa[9].x,  xa[9].y));
            xr[5] = make_uint2(cvt_pk(xa[10].x, xa[10].y), cvt_pk(xa[11].x, xa[11].y));
            xr[6] = make_uint2(cvt_pk(xa[12].x, xa[12].y), cvt_pk(xa[13].x, xa[13].y));
            xr[7] = make_uint2(cvt_pk(xa[14].x, xa[14].y), cvt_pk(xa[15].x, xa[15].y));
        }
        wsync();

        // ---- first-layer B fragments: B-slot j of tile t holds x[edge 32t+m][k(g,j)+16kt] ----
        frag_u xf[2][2];
        #pragma unroll
        for (int t = 0; t < 2; ++t) {
            const unsigned* er = (const unsigned*)&xrad[wv][32*t + m][0];
            #pragma unroll
            for (int kt = 0; kt < 2; ++kt) {
                const uint2 qa = *(const uint2*)&er[8*kt + 2*g];
                const uint2 qb = *(const uint2*)&er[8*kt + 4 + 2*g];
                xf[t][kt].u[0] = qa.x; xf[t][kt].u[1] = qa.y;
                xf[t][kt].u[2] = qb.x; xf[t][kt].u[3] = qb.y;
            }
        }

        // ---- layer 1 ----
        f32x16 acc0, acc1;
        acc0[0]=b1q0.x; acc0[1]=b1q0.y; acc0[2]=b1q0.z; acc0[3]=b1q0.w;
        acc0[4]=b1q1.x; acc0[5]=b1q1.y; acc0[6]=b1q1.z; acc0[7]=b1q1.w;
        acc0[8]=b1q2.x; acc0[9]=b1q2.y; acc0[10]=b1q2.z; acc0[11]=b1q2.w;
        acc0[12]=b1q3.x; acc0[13]=b1q3.y; acc0[14]=b1q3.z; acc0[15]=b1q3.w;
        acc1 = acc0;
        acc0 = __builtin_amdgcn_mfma_f32_32x32x16_bf16(wf1[0].v, xf[0][0].v, acc0, 0, 0, 0);
        acc0 = __builtin_amdgcn_mfma_f32_32x32x16_bf16(wf1[1].v, xf[0][1].v, acc0, 0, 0, 0);
        acc1 = __builtin_amdgcn_mfma_f32_32x32x16_bf16(wf1[0].v, xf[1][0].v, acc1, 0, 0, 0);
        acc1 = __builtin_amdgcn_mfma_f32_32x32x16_bf16(wf1[1].v, xf[1][1].v, acc1, 0, 0, 0);

        frag_u hf[2][2];
        #pragma unroll
        for (int t = 0; t < 2; ++t) {
            const f32x16 a = t ? acc1 : acc0;
            float h[16];
            #pragma unroll
            for (int r = 0; r < 16; ++r) h[r] = leaky(a[r]);
            hf[t][0].u[0] = cvt_pk(h[0], h[1]);   hf[t][0].u[1] = cvt_pk(h[2], h[3]);
            hf[t][0].u[2] = cvt_pk(h[4], h[5]);   hf[t][0].u[3] = cvt_pk(h[6], h[7]);
            hf[t][1].u[0] = cvt_pk(h[8], h[9]);   hf[t][1].u[1] = cvt_pk(h[10], h[11]);
            hf[t][1].u[2] = cvt_pk(h[12], h[13]); hf[t][1].u[3] = cvt_pk(h[14], h[15]);
        }

        // ---- layer 2 ----
        f32x16 c0, c1;
        c0[0]=b2q0.x; c0[1]=b2q0.y; c0[2]=b2q0.z; c0[3]=b2q0.w;
        c0[4]=b2q1.x; c0[5]=b2q1.y; c0[6]=b2q1.z; c0[7]=b2q1.w;
        c0[8]=b2q2.x; c0[9]=b2q2.y; c0[10]=b2q2.z; c0[11]=b2q2.w;
        c0[12]=b2q3.x; c0[13]=b2q3.y; c0[14]=b2q3.z; c0[15]=b2q3.w;
        c1 = c0;
        c0 = __builtin_amdgcn_mfma_f32_32x32x16_bf16(wf2[0].v, hf[0][0].v, c0, 0, 0, 0);
        c0 = __builtin_amdgcn_mfma_f32_32x32x16_bf16(wf2[1].v, hf[0][1].v, c0, 0, 0, 0);
        c1 = __builtin_amdgcn_mfma_f32_32x32x16_bf16(wf2[0].v, hf[1][0].v, c1, 0, 0, 0);
        c1 = __builtin_amdgcn_mfma_f32_32x32x16_bf16(wf2[1].v, hf[1][1].v, c1, 0, 0, 0);

        frag_u gf[2][2];
        #pragma unroll
        for (int t = 0; t < 2; ++t) {
            const f32x16 a = t ? c1 : c0;
            float h[16];
            #pragma unroll
            for (int r = 0; r < 16; ++r) h[r] = leaky(a[r]);
            gf[t][0].u[0] = cvt_pk(h[0], h[1]);   gf[t][0].u[1] = cvt_pk(h[2], h[3]);
            gf[t][0].u[2] = cvt_pk(h[4], h[5]);   gf[t][0].u[3] = cvt_pk(h[6], h[7]);
            gf[t][1].u[0] = cvt_pk(h[8], h[9]);   gf[t][1].u[1] = cvt_pk(h[10], h[11]);
            gf[t][1].u[2] = cvt_pk(h[12], h[13]); gf[t][1].u[3] = cvt_pk(h[14], h[15]);
        }

        // ---- layer 3 (no bias, no activation) ----
        f32x16 r0 = {}, r1 = {};
        r0 = __builtin_amdgcn_mfma_f32_32x32x16_bf16(wf3[0].v, gf[0][0].v, r0, 0, 0, 0);
        r0 = __builtin_amdgcn_mfma_f32_32x32x16_bf16(wf3[1].v, gf[0][1].v, r0, 0, 0, 0);
        r1 = __builtin_amdgcn_mfma_f32_32x32x16_bf16(wf3[0].v, gf[1][0].v, r1, 0, 0, 0);
        r1 = __builtin_amdgcn_mfma_f32_32x32x16_bf16(wf3[1].v, gf[1][1].v, r1, 0, 0, 0);

        // ---- write rad back (b64 stores) ----
        #pragma unroll
        for (int t = 0; t < 2; ++t) {
            const f32x16 a = t ? r1 : r0;
            float* rr = &xrad[wv][32*t + m][0];
            *(float2*)&rr[4*g]          = make_float2(a[0],  a[1]);
            *(float2*)&rr[4*g + 2]      = make_float2(a[2],  a[3]);
            *(float2*)&rr[8 + 4*g]      = make_float2(a[4],  a[5]);
            *(float2*)&rr[8 + 4*g + 2]  = make_float2(a[6],  a[7]);
            *(float2*)&rr[16 + 4*g]     = make_float2(a[8],  a[9]);
            *(float2*)&rr[16 + 4*g + 2] = make_float2(a[10], a[11]);
            *(float2*)&rr[24 + 4*g]     = make_float2(a[12], a[13]);
            *(float2*)&rr[24 + 4*g + 2] = make_float2(a[14], a[15]);
        }
        wsync();

        // ---- serial segmented reduce (persistent cur across batches) ----
        #pragma unroll 4
        for (int l = 0; l < 64; ++l) {
            const float4 rvn = rvn_lds[wv][l];          // uniform b128 broadcast
            const int nd = __float_as_int(rvn.w);       // wave-uniform
            const float rd = xrad[wv][l][i];
            if (nd != cur) {                            // wave-uniform branch
                if (cur >= 0) {
                    if (p == 0) {
                        atomicAdd(&A_a[cur*DA + i], accA);
                        atomicAdd(&out_v[(cur*DA + i)*3 + 0], a0);
                    } else {
                        atomicAdd(&out_v[(cur*DA + i)*3 + 1], a1);
                        atomicAdd(&out_v[(cur*DA + i)*3 + 2], a2);
                    }
                }
                accA = a0 = a1 = a2 = 0.0f;
                cur = nd;
            }
            accA += rd;
            a0 += rd * rvn.x;
            a1 += rd * rvn.y;
            a2 += rd * rvn.z;
        }
        wsync();   // reduce reads retired before next batch overwrites buffers
    }

    // final flush
    if (p == 0) {
        atomicAdd(&A_a[cur*DA + i], accA);
        atomicAdd(&out_v[(cur*DA + i)*3 + 0], a0);
    } else {
        atomicAdd(&out_v[(cur*DA + i)*3 + 1], a1);
        atomicAdd(&out_v[(cur*DA + i)*3 + 2], a2);
    }
}

// ---------------- phase B: out_v[n][v][d] = sum_a Wv[v][a] * A_v[n][a][d], in place ----------------

__global__ __launch_bounds__(256) void dt_node(
    const float* __restrict__ Wv,
    float* Av_out)   // aliased read+write, deliberately NOT restrict
{
    __shared__ float sWv[DA*DA];
    for (int i = threadIdx.x; i < DA*DA; i += 256) sWv[i] = Wv[i];
    __syncthreads();

    const int t = blockIdx.x * 256 + threadIdx.x;   // grid exactly NN*32/256
    const int n = t >> 5;
    const int v = t & 31;

    const float* av = Av_out + (size_t)n * (DA*3);
    float o0 = 0.0f, o1 = 0.0f, o2 = 0.0f;
    #pragma unroll
    for (int a = 0; a < DA; ++a) {
        const float w = sWv[v*DA + a];
        o0 += w * av[a*3 + 0];
        o1 += w * av[a*3 + 1];
        o2 += w * av[a*3 + 2];
    }
    __syncthreads();   // all loads of this block's nodes complete before any store
    float* o = Av_out + (size_t)n * (DA*3) + v*3;
    o[0] = o0; o[1] = o1; o[2] = o2;
}

// ---------------- legacy path (used only if ws too small for the new path) ----------------

__global__ __launch_bounds__(256) void k_hist_legacy(const int* __restrict__ src,
                                                     int* __restrict__ counts,
                                                     int* __restrict__ rank) {
    const int e = blockIdx.x * 256 + threadIdx.x;
    rank[e] = atomicAdd(&counts[src[e]], 1);
}

__global__ __launch_bounds__(256) void k_scan_legacy(const int* __restrict__ counts,
                                                     int* __restrict__ offsets) {
    __shared__ int part[256];
    const int CH = (NN + 255) / 256;
    const int t = threadIdx.x;
    const int base = t * CH;
    int s = 0;
    for (int k = 0; k < CH; ++k) { const int idx = base + k; if (idx < NN) s += counts[idx]; }
    part[t] = s;
    __syncthreads();
    if (t == 0) {
        int run = 0;
        for (int k = 0; k < 256; ++k) { const int v = part[k]; part[k] = run; run += v; }
    }
    __syncthreads();
    int run = part[t];
    for (int k = 0; k < CH; ++k) {
        const int idx = base + k;
        if (idx < NN) { offsets[idx] = run; run += counts[idx]; }
    }
    if (t == 255) offsets[NN] = run;
}

__global__ __launch_bounds__(256) void k_scatter_legacy(const int* __restrict__ src,
                                                        const int* __restrict__ offsets,
                                                        const int* __restrict__ rank,
                                                        int* __restrict__ edge_ids) {
    const int e = blockIdx.x * 256 + threadIdx.x;
    edge_ids[offsets[src[e]] + rank[e]] = e;
}

__global__ __launch_bounds__(256, 2) void dt_window_legacy(
    const float* __restrict__ r_ij,
    const float* __restrict__ res_emb,
    const int*   __restrict__ src,
    const int*   __restrict__ dst,
    const int*   __restrict__ edge_ids,
    const float* __restrict__ W1, const float* __restrict__ b1,
    const float* __restrict__ W2, const float* __restrict__ b2,
    const float* __restrict__ W3,
    float* __restrict__ A_a,
    float* __restrict__ out_v)
{
    __shared__ float  rad_lds[4][32][36];
    __shared__ float4 rvn_lds[4][64];

    const int tid  = threadIdx.x;
    const int wv   = tid >> 6;
    const int lane = tid & 63;
    const int slot = blockIdx.x * 256 + tid;

    const int eid  = edge_ids[slot];
    const int node = src[eid];

    const float rx = r_ij[(size_t)eid*3 + 0];
    const float ry = r_ij[(size_t)eid*3 + 1];
    const float rz = r_ij[(size_t)eid*3 + 2];
    const float dist = sqrtf(rx*rx + ry*ry + rz*rz);

    float xa[DA], xb[DA];
    #pragma unroll
    for (int mm = 0; mm < 8; ++mm) {
        float sph, cph;
        __sincosf(PI_R0 * (float)(mm + 1) * dist, &sph, &cph);
        xa[2*mm] = cph; xa[2*mm+1] = cph;
        xa[16+2*mm] = sph; xa[16+2*mm+1] = sph;
    }
    const float4* er = (const float4*)(res_emb + (size_t)dst[eid] * DA);
    #pragma unroll
    for (int q = 0; q < 8; ++q) {
        const float4 v = er[q];
        xa[q*4+0] += v.x; xa[q*4+1] += v.y; xa[q*4+2] += v.z; xa[q*4+3] += v.w;
    }
    #pragma unroll
    for (int i = 0; i < DA; ++i) {
        float acc = b1[i];
        #pragma unroll
        for (int j = 0; j < DA; ++j) acc += W1[i*DA + j] * xa[j];
        xb[i] = (acc >= 0.0f) ? acc : 0.1f * acc;
    }
    #pragma unroll
    for (int i = 0; i < DA; ++i) {
        float acc = b2[i];
        #pragma unroll
        for (int j = 0; j < DA; ++j) acc += W2[i*DA + j] * xb[j];
        xa[i] = (acc >= 0.0f) ? acc : 0.1f * acc;
    }
    #pragma unroll
    for (int i = 0; i < DA; ++i) {
        float acc = 0.0f;
        #pragma unroll
        for (int j = 0; j < DA; ++j) acc += W3[i*DA + j] * xa[j];
        xb[i] = acc;
    }

    const float qx = rx*1.4f, qy = ry*1.4f, qz = rz*1.4f;
    const float nq = sqrtf(qx*qx + qy*qy + qz*qz);
    const float e2 = __expf(2.0f * nq);
    const float sc = (nq > 0.0f)
        ? (e2 - 1.0f) * __builtin_amdgcn_rcpf((e2 + 1.0f) * nq)
        : 0.0f;

    rvn_lds[wv][lane] = make_float4(qx*sc, qy*sc, qz*sc, __int_as_float(node));

    const int p = lane >> 5;
    const int i = lane & 31;

    if (lane < 32) {
        float* rrow = rad_lds[wv][lane];
        #pragma unroll
        for (int q = 0; q < 8; ++q)
            *(float4*)&rrow[q*4] = make_float4(xb[q*4+0], xb[q*4+1], xb[q*4+2], xb[q*4+3]);
    }
    wsync();

    float accA = 0.0f, a0 = 0.0f, a1 = 0.0f, a2 = 0.0f;
    int cur = __float_as_int(rvn_lds[wv][0].w);

    #pragma unroll 4
    for (int l = 0; l < 32; ++l) {
        const float4 rvn = rvn_lds[wv][l];
        const int nd = __float_as_int(rvn.w);
        const float rd = rad_lds[wv][l][i];
        if (nd != cur) {
            if (p == 0) {
                atomicAdd(&A_a[cur*DA + i], accA);
                atomicAdd(&out_v[(cur*DA + i)*3 + 0], a0);
            } else {
                atomicAdd(&out_v[(cur*DA + i)*3 + 1], a1);
                atomicAdd(&out_v[(cur*DA + i)*3 + 2], a2);
            }
            accA = a0 = a1 = a2 = 0.0f;
            cur = nd;
        }
        accA += rd; a0 += rd*rvn.x; a1 += rd*rvn.y; a2 += rd*rvn.z;
    }
    wsync();
    if (lane >= 32) {
        float* rrow = rad_lds[wv][lane - 32];
        #pragma unroll
        for (int q = 0; q < 8; ++q)
            *(float4*)&rrow[q*4] = make_float4(xb[q*4+0], xb[q*4+1], xb[q*4+2], xb[q*4+3]);
    }
    wsync();
    #pragma unroll 4
    for (int l = 32; l < 64; ++l) {
        const float4 rvn = rvn_lds[wv][l];
        const int nd = __float_as_int(rvn.w);
        const float rd = rad_lds[wv][l - 32][i];
        if (nd != cur) {
            if (p == 0) {
                atomicAdd(&A_a[cur*DA + i], accA);
                atomicAdd(&out_v[(cur*DA + i)*3 + 0], a0);
            } else {
                atomicAdd(&out_v[(cur*DA + i)*3 + 1], a1);
                atomicAdd(&out_v[(cur*DA + i)*3 + 2], a2);
            }
            accA = a0 = a1 = a2 = 0.0f;
            cur = nd;
        }
        accA += rd; a0 += rd*rvn.x; a1 += rd*rvn.y; a2 += rd*rvn.z;
    }
    if (p == 0) {
        atomicAdd(&A_a[cur*DA + i], accA);
        atomicAdd(&out_v[(cur*DA + i)*3 + 0], a0);
    } else {
        atomicAdd(&out_v[(cur*DA + i)*3 + 1], a1);
        atomicAdd(&out_v[(cur*DA + i)*3 + 2], a2);
    }
}

// ---------------- launch ----------------

extern "C" void kernel_launch(void* const* d_in, const int* in_sizes, int n_in,
                              void* d_out, int out_size, void* d_ws, size_t ws_size,
                              hipStream_t stream) {
    const float* r_ij    = (const float*)d_in[0];
    const float* res_emb = (const float*)d_in[1];
    const int*   src     = (const int*)d_in[2];
    const int*   dst     = (const int*)d_in[3];
    const float* W1      = (const float*)d_in[4];
    const float* b1      = (const float*)d_in[5];
    const float* W2      = (const float*)d_in[6];
    const float* b2      = (const float*)d_in[7];
    const float* W3      = (const float*)d_in[8];
    const float* Wv      = (const float*)d_in[9];

    float* A_a   = (float*)d_out;                    // [NN][32]
    float* out_v = (float*)d_out + (size_t)NN * DA;  // [NN][32][3]

    // new-path ws: rec[NE*4] | emb16[NN*16] | counts[NB] | offsets[NB+1] | rank[NE] | bsum[1024] | bbase[1024]
    const size_t need_new = ((size_t)NE*4 + (size_t)NN*16 + NB + NB + 1 + NE + 1024 + 1024) * sizeof(int);
    const size_t need_leg = ((size_t)NN + NN + 1 + NE + NE) * sizeof(int);

    // output is accumulated into -> must be zeroed every call
    hipMemsetAsync(d_out, 0, (size_t)out_size * sizeof(float), stream);

    if (ws_size >= need_new) {
        uint4*    rec     = (uint4*)d_ws;
        unsigned* emb16   = (unsigned*)(rec + NE);
        int*      counts  = (int*)(emb16 + (size_t)NN*16);
        int*      offsets = counts + NB;
        int*      rank    = offsets + NB + 1;
        int*      bsum    = rank + NE;
        int*      bbase   = bsum + 1024;

        hipMemsetAsync(counts, 0, (size_t)NB * sizeof(int), stream);
        k_hist  <<<NE / 256, 256, 0, stream>>>(src, counts, rank);
        k_scanA <<<SCANB_BLOCKS, 256, 0, stream>>>(counts, bsum);
        k_scanB <<<1, 1024, 0, stream>>>(bsum, bbase);
        k_scanC <<<SCANB_BLOCKS, 256, 0, stream>>>(counts, bbase, offsets);
        k_embcvt<<<(NN*16) / 256, 256, 0, stream>>>(res_emb, emb16);
        k_prep  <<<NE / 256, 256, 0, stream>>>(r_ij, src, dst, offsets, rank, rec);
        dt_window<<<NE / 512, 256, 0, stream>>>(rec, emb16,
                                                W1, b1, W2, b2, W3, A_a, out_v);
        dt_node <<<(NN * DA) / 256, 256, 0, stream>>>(Wv, out_v);
    } else if (ws_size >= need_leg) {
        int* counts   = (int*)d_ws;
        int* offsets  = counts + NN;
        int* rank     = offsets + NN + 1;
        int* edge_ids = rank + NE;

        hipMemsetAsync(counts, 0, (size_t)NN * sizeof(int), stream);
        k_hist_legacy   <<<NE / 256, 256, 0, stream>>>(src, counts, rank);
        k_scan_legacy   <<<1, 256, 0, stream>>>(counts, offsets);
        k_scatter_legacy<<<NE / 256, 256, 0, stream>>>(src, offsets, rank, edge_ids);
        dt_window_legacy<<<NE / 256, 256, 0, stream>>>(r_ij, res_emb, src, dst, edge_ids,
                                                       W1, b1, W2, b2, W3, A_a, out_v);
        dt_node         <<<(NN * DA) / 256, 256, 0, stream>>>(Wv, out_v);
    }
}

// Round 14
// 231.956 us; speedup vs baseline: 1.1214x; 1.0198x over previous
//
#include <hip/hip_runtime.h>
#include <math.h>

// DisplacementTensors: per-edge radial-MLP + segment-sum to nodes + per-node linear map.
// N_NODES=50000, N_EDGES=1600000, DIM_A=DIM_V=32, R0=5, LEAK=0.1
//
// Round 14: r13's chain restructure had a fatal constant: k_init zeroed only
// 400000 uint4 = exactly A_a; out_v was never zeroed -> timed replays
// accumulated onto harness poison (first check passed, re-validation failed).
// Fix: OUTQ4 = out_size/4 = 1,600,000. Chain experiment otherwise unchanged:
//  - bins = NN (r9 best), k_init replaces 2 memsets, hist+embcvt fused,
//    scanB folded into scanC (inline 196-entry base scan). 7 dispatches.
//  - dt_window FROZEN from r12 (94us control).
//
// d_out layout: A_a [50000*32] floats, then out_v [50000*32*3] floats.
// ws (new path, ~36MB): rec u32[NE*4] | emb16 u32[NN*16] | counts[NN] |
//                       offsets[NN+1] | rank[NE] | bsum[256]

#define NN 50000
#define NE 1600000
#define DA 32
#define PI_R0 0.62831853071795864769f  // pi / 5
#define SCAN_BLOCKS 196                // ceil(NN/256)
#define HIST_BLOCKS (NE/256)           // 6250
#define EMB_BLOCKS  ((NN*16)/256)      // 3125
#define RSTRIDE 34                     // xrad row stride in floats (136B, b64-aligned)
#define OUTQ4 1600000                  // d_out as uint4: 6.4M floats / 4
#define CNTQ4 12500                    // counts as uint4: 50000 ints / 4

typedef float v2f __attribute__((ext_vector_type(2)));
typedef short bf16x8 __attribute__((ext_vector_type(8)));   // 8 bf16 = 4 VGPRs
typedef float f32x16 __attribute__((ext_vector_type(16)));  // MFMA C/D

union frag_u { unsigned u[4]; bf16x8 v; };

__device__ __forceinline__ void wsync() {
    // intra-wave LDS handoff: wave is lockstep; drain the DS queue.
    asm volatile("s_waitcnt lgkmcnt(0)" ::: "memory");
}

__device__ __forceinline__ unsigned cvt_pk(float lo, float hi) {
    unsigned r;
    asm("v_cvt_pk_bf16_f32 %0, %1, %2" : "=v"(r) : "v"(lo), "v"(hi));
    return r;   // lo -> low 16, hi -> high 16
}

__device__ __forceinline__ float leaky(float x) {
    return fmaxf(x, 0.0f) + 0.1f * fminf(x, 0.0f);
}

// round-to-nearest-ish bf16 (add half-ulp then truncate)
__device__ __forceinline__ unsigned bf_hi(float x) {
    return (__float_as_uint(x) + 0x8000u) >> 16;
}
__device__ __forceinline__ unsigned bf_pack2(float lo, float hi) {
    return bf_hi(lo) | ((__float_as_uint(hi) + 0x8000u) & 0xffff0000u);
}

// ---------------- init: zero d_out (6.4M floats = 1.6M uint4) + counts ----------------

__global__ __launch_bounds__(256) void k_init(uint4* __restrict__ outq,
                                              uint4* __restrict__ cntq) {
    const uint4 z = make_uint4(0, 0, 0, 0);
    const int stride = gridDim.x * 256;
    for (int i = blockIdx.x * 256 + threadIdx.x; i < OUTQ4 + CNTQ4; i += stride) {
        if (i < OUTQ4) outq[i] = z;
        else           cntq[i - OUTQ4] = z;
    }
}

// ---------------- hist + embcvt fused (disjoint block ranges) ----------------

__global__ __launch_bounds__(256) void k_hist_emb(const int* __restrict__ src,
                                                  int* __restrict__ counts,
                                                  int* __restrict__ rank,
                                                  const float* __restrict__ emb,
                                                  unsigned* __restrict__ emb16) {
    const int b = blockIdx.x;
    if (b < HIST_BLOCKS) {
        const int e = b * 256 + threadIdx.x;
        rank[e] = atomicAdd(&counts[src[e]], 1);
    } else {
        const int t = (b - HIST_BLOCKS) * 256 + threadIdx.x;   // < NN*16 exactly
        emb16[t] = bf_pack2(emb[2*t], emb[2*t + 1]);
    }
}

// ---------------- scan: per-block reduce, then scanC with inline base ----------------

__global__ __launch_bounds__(256) void k_scanA(const int* __restrict__ counts,
                                               int* __restrict__ bsum) {
    __shared__ int red[256];
    const int t = threadIdx.x;
    const int idx = blockIdx.x * 256 + t;
    red[t] = (idx < NN) ? counts[idx] : 0;
    __syncthreads();
    #pragma unroll
    for (int off = 128; off > 0; off >>= 1) {
        if (t < off) red[t] += red[t + off];
        __syncthreads();
    }
    if (t == 0) bsum[blockIdx.x] = red[0];
}

__global__ __launch_bounds__(256) void k_scanC(const int* __restrict__ counts,
                                               const int* __restrict__ bsum,
                                               int* __restrict__ offsets) {
    __shared__ int sb[256];
    __shared__ int s[256];
    const int t = threadIdx.x;

    // inline block-base: inclusive scan of bsum[0..195]
    const int bv = (t < SCAN_BLOCKS) ? bsum[t] : 0;
    sb[t] = bv;
    __syncthreads();
    #pragma unroll
    for (int off = 1; off < 256; off <<= 1) {
        const int x = sb[t] + ((t >= off) ? sb[t - off] : 0);
        __syncthreads();
        sb[t] = x;
        __syncthreads();
    }
    const int base = (blockIdx.x > 0) ? sb[blockIdx.x - 1] : 0;

    // local scan of this block's counts
    const int idx = blockIdx.x * 256 + t;
    const int v = (idx < NN) ? counts[idx] : 0;
    s[t] = v;
    __syncthreads();
    #pragma unroll
    for (int off = 1; off < 256; off <<= 1) {
        const int x = s[t] + ((t >= off) ? s[t - off] : 0);
        __syncthreads();
        s[t] = x;
        __syncthreads();
    }
    const int excl = s[t] - v + base;
    if (idx < NN) offsets[idx] = excl;
    if (idx == NN - 1) offsets[NN] = excl + v;   // == NE
}

// scatter + per-edge precompute: sequential reads, random fire-and-forget writes.
// rec = {dist f32, vx|vy bf16x2, vz bf16, src u16 | dst u16 << 16}
__global__ __launch_bounds__(256) void k_prep(
    const float* __restrict__ r_ij,
    const int*   __restrict__ src,
    const int*   __restrict__ dst,
    const int*   __restrict__ offsets,
    const int*   __restrict__ rank,
    uint4* __restrict__ rec)
{
    const int e = blockIdx.x * 256 + threadIdx.x;   // grid exactly NE/256
    const int s = src[e];
    const int slot = offsets[s] + rank[e];

    const float rx = r_ij[(size_t)e*3 + 0];
    const float ry = r_ij[(size_t)e*3 + 1];
    const float rz = r_ij[(size_t)e*3 + 2];
    const float dist = sqrtf(rx*rx + ry*ry + rz*rz);

    const float nq = 1.4f * dist;
    const float e2 = __expf(2.0f * nq);
    const float sc14 = (nq > 0.0f)
        ? 1.4f * (e2 - 1.0f) * __builtin_amdgcn_rcpf((e2 + 1.0f) * nq)
        : 0.0f;

    uint4 r;
    r.x = __float_as_uint(dist);
    r.y = bf_pack2(rx * sc14, ry * sc14);
    r.z = bf_hi(rz * sc14);
    r.w = (unsigned)s | ((unsigned)dst[e] << 16);   // both < 65536
    rec[slot] = r;
}

// ---------------- phase A: MFMA MLP over CSR windows + segmented flush ----------------
// block = 256 = 4 waves; wave owns 128 contiguous CSR slots, processed as
// 2 batches of 64 (one slot per lane per batch). Per batch: 12x
// mfma_f32_32x32x16_bf16 (k-slot labeling k(g,j)=4g+(j&3)+8*(j>>2) chains
// layer L's D regs directly into layer L+1's B frag), then a serial
// segmented reduce with cur/accumulators PERSISTENT across batches.
// [FROZEN from round 12.]

__global__ __launch_bounds__(256, 2) void dt_window(
    const uint4*    __restrict__ rec,
    const unsigned* __restrict__ emb16,
    const float* __restrict__ W1, const float* __restrict__ b1,
    const float* __restrict__ W2, const float* __restrict__ b2,
    const float* __restrict__ W3,
    float* __restrict__ A_a,    // [NN][32]  (accumulates, pre-zeroed)
    float* __restrict__ out_v)  // [NN][32][3] (accumulates raw A_v, pre-zeroed)
{
    // rows are 136B: b64-aligned; banks (34*row + col) % 32 = (2*row + col) % 32
    __shared__ float  xrad[4][64][RSTRIDE];   // [wave][edge][dim(+pad)]
    __shared__ float4 rvn_lds[4][64];         // [wave][slot] = (vx, vy, vz, bits(node))

    const int tid   = threadIdx.x;
    const int wv    = tid >> 6;
    const int lane  = tid & 63;
    const int g     = lane >> 5;          // k-group / lane half
    const int m     = lane & 31;          // row (A) / col (B) within tile
    const int wbase = blockIdx.x * 512 + wv * 128;   // grid exactly NE/512

    // ---- W fragments, loaded once: wf[layer][kt], A-slot j holds W[m][k(g,j)+16kt] ----
    frag_u wf1[2], wf2[2], wf3[2];
    #pragma unroll
    for (int kt = 0; kt < 2; ++kt) {
        const float4 a1 = *(const float4*)&W1[m*DA + 16*kt + 4*g];
        const float4 c1 = *(const float4*)&W1[m*DA + 16*kt + 8 + 4*g];
        wf1[kt].u[0] = cvt_pk(a1.x, a1.y); wf1[kt].u[1] = cvt_pk(a1.z, a1.w);
        wf1[kt].u[2] = cvt_pk(c1.x, c1.y); wf1[kt].u[3] = cvt_pk(c1.z, c1.w);
        const float4 a2 = *(const float4*)&W2[m*DA + 16*kt + 4*g];
        const float4 c2 = *(const float4*)&W2[m*DA + 16*kt + 8 + 4*g];
        wf2[kt].u[0] = cvt_pk(a2.x, a2.y); wf2[kt].u[1] = cvt_pk(a2.z, a2.w);
        wf2[kt].u[2] = cvt_pk(c2.x, c2.y); wf2[kt].u[3] = cvt_pk(c2.z, c2.w);
        const float4 a3 = *(const float4*)&W3[m*DA + 16*kt + 4*g];
        const float4 c3 = *(const float4*)&W3[m*DA + 16*kt + 8 + 4*g];
        wf3[kt].u[0] = cvt_pk(a3.x, a3.y); wf3[kt].u[1] = cvt_pk(a3.z, a3.w);
        wf3[kt].u[2] = cvt_pk(c3.x, c3.y); wf3[kt].u[3] = cvt_pk(c3.z, c3.w);
    }

    // bias per D-reg r: dim d(r,g) = (r&3) + 8*(r>>2) + 4g
    const float4 b1q0 = *(const float4*)&b1[4*g];
    const float4 b1q1 = *(const float4*)&b1[8 + 4*g];
    const float4 b1q2 = *(const float4*)&b1[16 + 4*g];
    const float4 b1q3 = *(const float4*)&b1[24 + 4*g];
    const float4 b2q0 = *(const float4*)&b2[4*g];
    const float4 b2q1 = *(const float4*)&b2[8 + 4*g];
    const float4 b2q2 = *(const float4*)&b2[16 + 4*g];
    const float4 b2q3 = *(const float4*)&b2[24 + 4*g];

    const int p = g;
    const int i = m;
    float accA = 0.0f, a0 = 0.0f, a1 = 0.0f, a2 = 0.0f;
    int cur = -1;   // sentinel; node ids >= 0

    #pragma unroll
    for (int b = 0; b < 2; ++b) {
        const int slot = wbase + b*64 + lane;

        // ---- per-edge input: radial encode + bf16 emb gather ----
        const uint4 rc = rec[slot];                // sequential b128
        const float dist = __uint_as_float(rc.x);
        const float vx = __uint_as_float(rc.y << 16);
        const float vy = __uint_as_float(rc.y & 0xffff0000u);
        const float vz = __uint_as_float(rc.z << 16);
        const int  node = (int)(rc.w & 0xffffu);
        const int  dn   = (int)(rc.w >> 16);

        v2f xa[16];
        #pragma unroll
        for (int mm = 0; mm < 8; ++mm) {
            float sph, cph;
            __sincosf(PI_R0 * (float)(mm + 1) * dist, &sph, &cph);
            xa[mm]     = (v2f){cph, cph};
            xa[8 + mm] = (v2f){sph, sph};
        }
        const uint4* ep = (const uint4*)(emb16 + (size_t)dn * 16);
        #pragma unroll
        for (int q = 0; q < 4; ++q) {
            const uint4 u = ep[q];
            xa[q*4 + 0] += (v2f){__uint_as_float(u.x << 16), __uint_as_float(u.x & 0xffff0000u)};
            xa[q*4 + 1] += (v2f){__uint_as_float(u.y << 16), __uint_as_float(u.y & 0xffff0000u)};
            xa[q*4 + 2] += (v2f){__uint_as_float(u.z << 16), __uint_as_float(u.z & 0xffff0000u)};
            xa[q*4 + 3] += (v2f){__uint_as_float(u.w << 16), __uint_as_float(u.w & 0xffff0000u)};
        }

        rvn_lds[wv][lane] = make_float4(vx, vy, vz, __int_as_float(node));

        // pack x to bf16 pairs and stash (8 x b64)
        {
            uint2* xr = (uint2*)&xrad[wv][lane][0];
            xr[0] = make_uint2(cvt_pk(xa[0].x,  xa[0].y),  cvt_pk(xa[1].x,  xa[1].y));
            xr[1] = make_uint2(cvt_pk(xa[2].x,  xa[2].y),  cvt_pk(xa[3].x,  xa[3].y));
            xr[2] = make_uint2(cvt_pk(xa[4].x,  xa[4].y),  cvt_pk(xa[5].x,  xa[5].y));
            xr[3] = make_uint2(cvt_pk(xa[6].x,  xa[6].y),  cvt_pk(xa[7].x,  xa[7].y));
            xr[4] = make_uint2(cvt_pk(xa[8].x,  xa[8].y),  cvt_pk(xa[9].x,  xa[9].y));
            xr[5] = make_uint2(cvt_pk(xa[10].x, xa[10].y), cvt_pk(xa[11].x, xa[11].y));
            xr[6] = make_uint2(cvt_pk(xa[12].x, xa[12].y), cvt_pk(xa[13].x, xa[13].y));
            xr[7] = make_uint2(cvt_pk(xa[14].x, xa[14].y), cvt_pk(xa[15].x, xa[15].y));
        }
        wsync();

        // ---- first-layer B fragments: B-slot j of tile t holds x[edge 32t+m][k(g,j)+16kt] ----
        frag_u xf[2][2];
        #pragma unroll
        for (int t = 0; t < 2; ++t) {
            const unsigned* er = (const unsigned*)&xrad[wv][32*t + m][0];
            #pragma unroll
            for (int kt = 0; kt < 2; ++kt) {
                const uint2 qa = *(const uint2*)&er[8*kt + 2*g];
                const uint2 qb = *(const uint2*)&er[8*kt + 4 + 2*g];
                xf[t][kt].u[0] = qa.x; xf[t][kt].u[1] = qa.y;
                xf[t][kt].u[2] = qb.x; xf[t][kt].u[3] = qb.y;
            }
        }

        // ---- layer 1 ----
        f32x16 acc0, acc1;
        acc0[0]=b1q0.x; acc0[1]=b1q0.y; acc0[2]=b1q0.z; acc0[3]=b1q0.w;
        acc0[4]=b1q1.x; acc0[5]=b1q1.y; acc0[6]=b1q1.z; acc0[7]=b1q1.w;
        acc0[8]=b1q2.x; acc0[9]=b1q2.y; acc0[10]=b1q2.z; acc0[11]=b1q2.w;
        acc0[12]=b1q3.x; acc0[13]=b1q3.y; acc0[14]=b1q3.z; acc0[15]=b1q3.w;
        acc1 = acc0;
        acc0 = __builtin_amdgcn_mfma_f32_32x32x16_bf16(wf1[0].v, xf[0][0].v, acc0, 0, 0, 0);
        acc0 = __builtin_amdgcn_mfma_f32_32x32x16_bf16(wf1[1].v, xf[0][1].v, acc0, 0, 0, 0);
        acc1 = __builtin_amdgcn_mfma_f32_32x32x16_bf16(wf1[0].v, xf[1][0].v, acc1, 0, 0, 0);
        acc1 = __builtin_amdgcn_mfma_f32_32x32x16_bf16(wf1[1].v, xf[1][1].v, acc1, 0, 0, 0);

        frag_u hf[2][2];
        #pragma unroll
        for (int t = 0; t < 2; ++t) {
            const f32x16 a = t ? acc1 : acc0;
            float h[16];
            #pragma unroll
            for (int r = 0; r < 16; ++r) h[r] = leaky(a[r]);
            hf[t][0].u[0] = cvt_pk(h[0], h[1]);   hf[t][0].u[1] = cvt_pk(h[2], h[3]);
            hf[t][0].u[2] = cvt_pk(h[4], h[5]);   hf[t][0].u[3] = cvt_pk(h[6], h[7]);
            hf[t][1].u[0] = cvt_pk(h[8], h[9]);   hf[t][1].u[1] = cvt_pk(h[10], h[11]);
            hf[t][1].u[2] = cvt_pk(h[12], h[13]); hf[t][1].u[3] = cvt_pk(h[14], h[15]);
        }

        // ---- layer 2 ----
        f32x16 c0, c1;
        c0[0]=b2q0.x; c0[1]=b2q0.y; c0[2]=b2q0.z; c0[3]=b2q0.w;
        c0[4]=b2q1.x; c0[5]=b2q1.y; c0[6]=b2q1.z; c0[7]=b2q1.w;
        c0[8]=b2q2.x; c0[9]=b2q2.y; c0[10]=b2q2.z; c0[11]=b2q2.w;
        c0[12]=b2q3.x; c0[13]=b2q3.y; c0[14]=b2q3.z; c0[15]=b2q3.w;
        c1 = c0;
        c0 = __builtin_amdgcn_mfma_f32_32x32x16_bf16(wf2[0].v, hf[0][0].v, c0, 0, 0, 0);
        c0 = __builtin_amdgcn_mfma_f32_32x32x16_bf16(wf2[1].v, hf[0][1].v, c0, 0, 0, 0);
        c1 = __builtin_amdgcn_mfma_f32_32x32x16_bf16(wf2[0].v, hf[1][0].v, c1, 0, 0, 0);
        c1 = __builtin_amdgcn_mfma_f32_32x32x16_bf16(wf2[1].v, hf[1][1].v, c1, 0, 0, 0);

        frag_u gf[2][2];
        #pragma unroll
        for (int t = 0; t < 2; ++t) {
            const f32x16 a = t ? c1 : c0;
            float h[16];
            #pragma unroll
            for (int r = 0; r < 16; ++r) h[r] = leaky(a[r]);
            gf[t][0].u[0] = cvt_pk(h[0], h[1]);   gf[t][0].u[1] = cvt_pk(h[2], h[3]);
            gf[t][0].u[2] = cvt_pk(h[4], h[5]);   gf[t][0].u[3] = cvt_pk(h[6], h[7]);
            gf[t][1].u[0] = cvt_pk(h[8], h[9]);   gf[t][1].u[1] = cvt_pk(h[10], h[11]);
            gf[t][1].u[2] = cvt_pk(h[12], h[13]); gf[t][1].u[3] = cvt_pk(h[14], h[15]);
        }

        // ---- layer 3 (no bias, no activation) ----
        f32x16 r0 = {}, r1 = {};
        r0 = __builtin_amdgcn_mfma_f32_32x32x16_bf16(wf3[0].v, gf[0][0].v, r0, 0, 0, 0);
        r0 = __builtin_amdgcn_mfma_f32_32x32x16_bf16(wf3[1].v, gf[0][1].v, r0, 0, 0, 0);
        r1 = __builtin_amdgcn_mfma_f32_32x32x16_bf16(wf3[0].v, gf[1][0].v, r1, 0, 0, 0);
        r1 = __builtin_amdgcn_mfma_f32_32x32x16_bf16(wf3[1].v, gf[1][1].v, r1, 0, 0, 0);

        // ---- write rad back (b64 stores) ----
        #pragma unroll
        for (int t = 0; t < 2; ++t) {
            const f32x16 a = t ? r1 : r0;
            float* rr = &xrad[wv][32*t + m][0];
            *(float2*)&rr[4*g]          = make_float2(a[0],  a[1]);
            *(float2*)&rr[4*g + 2]      = make_float2(a[2],  a[3]);
            *(float2*)&rr[8 + 4*g]      = make_float2(a[4],  a[5]);
            *(float2*)&rr[8 + 4*g + 2]  = make_float2(a[6],  a[7]);
            *(float2*)&rr[16 + 4*g]     = make_float2(a[8],  a[9]);
            *(float2*)&rr[16 + 4*g + 2] = make_float2(a[10], a[11]);
            *(float2*)&rr[24 + 4*g]     = make_float2(a[12], a[13]);
            *(float2*)&rr[24 + 4*g + 2] = make_float2(a[14], a[15]);
        }
        wsync();

        // ---- serial segmented reduce (persistent cur across batches) ----
        #pragma unroll 4
        for (int l = 0; l < 64; ++l) {
            const float4 rvn = rvn_lds[wv][l];          // uniform b128 broadcast
            const int nd = __float_as_int(rvn.w);       // wave-uniform
            const float rd = xrad[wv][l][i];
            if (nd != cur) {                            // wave-uniform branch
                if (cur >= 0) {
                    if (p == 0) {
                        atomicAdd(&A_a[cur*DA + i], accA);
                        atomicAdd(&out_v[(cur*DA + i)*3 + 0], a0);
                    } else {
                        atomicAdd(&out_v[(cur*DA + i)*3 + 1], a1);
                        atomicAdd(&out_v[(cur*DA + i)*3 + 2], a2);
                    }
                }
                accA = a0 = a1 = a2 = 0.0f;
                cur = nd;
            }
            accA += rd;
            a0 += rd * rvn.x;
            a1 += rd * rvn.y;
            a2 += rd * rvn.z;
        }
        wsync();   // reduce reads retired before next batch overwrites buffers
    }

    // final flush
    if (p == 0) {
        atomicAdd(&A_a[cur*DA + i], accA);
        atomicAdd(&out_v[(cur*DA + i)*3 + 0], a0);
    } else {
        atomicAdd(&out_v[(cur*DA + i)*3 + 1], a1);
        atomicAdd(&out_v[(cur*DA + i)*3 + 2], a2);
    }
}

// ---------------- phase B: out_v[n][v][d] = sum_a Wv[v][a] * A_v[n][a][d], in place ----------------

__global__ __launch_bounds__(256) void dt_node(
    const float* __restrict__ Wv,
    float* Av_out)   // aliased read+write, deliberately NOT restrict
{
    __shared__ float sWv[DA*DA];
    for (int i = threadIdx.x; i < DA*DA; i += 256) sWv[i] = Wv[i];
    __syncthreads();

    const int t = blockIdx.x * 256 + threadIdx.x;   // grid exactly NN*32/256
    const int n = t >> 5;
    const int v = t & 31;

    const float* av = Av_out + (size_t)n * (DA*3);
    float o0 = 0.0f, o1 = 0.0f, o2 = 0.0f;
    #pragma unroll
    for (int a = 0; a < DA; ++a) {
        const float w = sWv[v*DA + a];
        o0 += w * av[a*3 + 0];
        o1 += w * av[a*3 + 1];
        o2 += w * av[a*3 + 2];
    }
    __syncthreads();   // all loads of this block's nodes complete before any store
    float* o = Av_out + (size_t)n * (DA*3) + v*3;
    o[0] = o0; o[1] = o1; o[2] = o2;
}

// ---------------- legacy path (used only if ws too small for the new path) ----------------

__global__ __launch_bounds__(256) void k_hist_legacy(const int* __restrict__ src,
                                                     int* __restrict__ counts,
                                                     int* __restrict__ rank) {
    const int e = blockIdx.x * 256 + threadIdx.x;
    rank[e] = atomicAdd(&counts[src[e]], 1);
}

__global__ __launch_bounds__(256) void k_scan_legacy(const int* __restrict__ counts,
                                                     int* __restrict__ offsets) {
    __shared__ int part[256];
    const int CH = (NN + 255) / 256;
    const int t = threadIdx.x;
    const int base = t * CH;
    int s = 0;
    for (int k = 0; k < CH; ++k) { const int idx = base + k; if (idx < NN) s += counts[idx]; }
    part[t] = s;
    __syncthreads();
    if (t == 0) {
        int run = 0;
        for (int k = 0; k < 256; ++k) { const int v = part[k]; part[k] = run; run += v; }
    }
    __syncthreads();
    int run = part[t];
    for (int k = 0; k < CH; ++k) {
        const int idx = base + k;
        if (idx < NN) { offsets[idx] = run; run += counts[idx]; }
    }
    if (t == 255) offsets[NN] = run;
}

__global__ __launch_bounds__(256) void k_scatter_legacy(const int* __restrict__ src,
                                                        const int* __restrict__ offsets,
                                                        const int* __restrict__ rank,
                                                        int* __restrict__ edge_ids) {
    const int e = blockIdx.x * 256 + threadIdx.x;
    edge_ids[offsets[src[e]] + rank[e]] = e;
}

__global__ __launch_bounds__(256, 2) void dt_window_legacy(
    const float* __restrict__ r_ij,
    const float* __restrict__ res_emb,
    const int*   __restrict__ src,
    const int*   __restrict__ dst,
    const int*   __restrict__ edge_ids,
    const float* __restrict__ W1, const float* __restrict__ b1,
    const float* __restrict__ W2, const float* __restrict__ b2,
    const float* __restrict__ W3,
    float* __restrict__ A_a,
    float* __restrict__ out_v)
{
    __shared__ float  rad_lds[4][32][36];
    __shared__ float4 rvn_lds[4][64];

    const int tid  = threadIdx.x;
    const int wv   = tid >> 6;
    const int lane = tid & 63;
    const int slot = blockIdx.x * 256 + tid;

    const int eid  = edge_ids[slot];
    const int node = src[eid];

    const float rx = r_ij[(size_t)eid*3 + 0];
    const float ry = r_ij[(size_t)eid*3 + 1];
    const float rz = r_ij[(size_t)eid*3 + 2];
    const float dist = sqrtf(rx*rx + ry*ry + rz*rz);

    float xa[DA], xb[DA];
    #pragma unroll
    for (int mm = 0; mm < 8; ++mm) {
        float sph, cph;
        __sincosf(PI_R0 * (float)(mm + 1) * dist, &sph, &cph);
        xa[2*mm] = cph; xa[2*mm+1] = cph;
        xa[16+2*mm] = sph; xa[16+2*mm+1] = sph;
    }
    const float4* er = (const float4*)(res_emb + (size_t)dst[eid] * DA);
    #pragma unroll
    for (int q = 0; q < 8; ++q) {
        const float4 v = er[q];
        xa[q*4+0] += v.x; xa[q*4+1] += v.y; xa[q*4+2] += v.z; xa[q*4+3] += v.w;
    }
    #pragma unroll
    for (int i = 0; i < DA; ++i) {
        float acc = b1[i];
        #pragma unroll
        for (int j = 0; j < DA; ++j) acc += W1[i*DA + j] * xa[j];
        xb[i] = (acc >= 0.0f) ? acc : 0.1f * acc;
    }
    #pragma unroll
    for (int i = 0; i < DA; ++i) {
        float acc = b2[i];
        #pragma unroll
        for (int j = 0; j < DA; ++j) acc += W2[i*DA + j] * xb[j];
        xa[i] = (acc >= 0.0f) ? acc : 0.1f * acc;
    }
    #pragma unroll
    for (int i = 0; i < DA; ++i) {
        float acc = 0.0f;
        #pragma unroll
        for (int j = 0; j < DA; ++j) acc += W3[i*DA + j] * xa[j];
        xb[i] = acc;
    }

    const float qx = rx*1.4f, qy = ry*1.4f, qz = rz*1.4f;
    const float nq = sqrtf(qx*qx + qy*qy + qz*qz);
    const float e2 = __expf(2.0f * nq);
    const float sc = (nq > 0.0f)
        ? (e2 - 1.0f) * __builtin_amdgcn_rcpf((e2 + 1.0f) * nq)
        : 0.0f;

    rvn_lds[wv][lane] = make_float4(qx*sc, qy*sc, qz*sc, __int_as_float(node));

    const int p = lane >> 5;
    const int i = lane & 31;

    if (lane < 32) {
        float* rrow = rad_lds[wv][lane];
        #pragma unroll
        for (int q = 0; q < 8; ++q)
            *(float4*)&rrow[q*4] = make_float4(xb[q*4+0], xb[q*4+1], xb[q*4+2], xb[q*4+3]);
    }
    wsync();

    float accA = 0.0f, a0 = 0.0f, a1 = 0.0f, a2 = 0.0f;
    int cur = __float_as_int(rvn_lds[wv][0].w);

    #pragma unroll 4
    for (int l = 0; l < 32; ++l) {
        const float4 rvn = rvn_lds[wv][l];
        const int nd = __float_as_int(rvn.w);
        const float rd = rad_lds[wv][l][i];
        if (nd != cur) {
            if (p == 0) {
                atomicAdd(&A_a[cur*DA + i], accA);
                atomicAdd(&out_v[(cur*DA + i)*3 + 0], a0);
            } else {
                atomicAdd(&out_v[(cur*DA + i)*3 + 1], a1);
                atomicAdd(&out_v[(cur*DA + i)*3 + 2], a2);
            }
            accA = a0 = a1 = a2 = 0.0f;
            cur = nd;
        }
        accA += rd; a0 += rd*rvn.x; a1 += rd*rvn.y; a2 += rd*rvn.z;
    }
    wsync();
    if (lane >= 32) {
        float* rrow = rad_lds[wv][lane - 32];
        #pragma unroll
        for (int q = 0; q < 8; ++q)
            *(float4*)&rrow[q*4] = make_float4(xb[q*4+0], xb[q*4+1], xb[q*4+2], xb[q*4+3]);
    }
    wsync();
    #pragma unroll 4
    for (int l = 32; l < 64; ++l) {
        const float4 rvn = rvn_lds[wv][l];
        const int nd = __float_as_int(rvn.w);
        const float rd = rad_lds[wv][l - 32][i];
        if (nd != cur) {
            if (p == 0) {
                atomicAdd(&A_a[cur*DA + i], accA);
                atomicAdd(&out_v[(cur*DA + i)*3 + 0], a0);
            } else {
                atomicAdd(&out_v[(cur*DA + i)*3 + 1], a1);
                atomicAdd(&out_v[(cur*DA + i)*3 + 2], a2);
            }
            accA = a0 = a1 = a2 = 0.0f;
            cur = nd;
        }
        accA += rd; a0 += rd*rvn.x; a1 += rd*rvn.y; a2 += rd*rvn.z;
    }
    if (p == 0) {
        atomicAdd(&A_a[cur*DA + i], accA);
        atomicAdd(&out_v[(cur*DA + i)*3 + 0], a0);
    } else {
        atomicAdd(&out_v[(cur*DA + i)*3 + 1], a1);
        atomicAdd(&out_v[(cur*DA + i)*3 + 2], a2);
    }
}

// ---------------- launch ----------------

extern "C" void kernel_launch(void* const* d_in, const int* in_sizes, int n_in,
                              void* d_out, int out_size, void* d_ws, size_t ws_size,
                              hipStream_t stream) {
    const float* r_ij    = (const float*)d_in[0];
    const float* res_emb = (const float*)d_in[1];
    const int*   src     = (const int*)d_in[2];
    const int*   dst     = (const int*)d_in[3];
    const float* W1      = (const float*)d_in[4];
    const float* b1      = (const float*)d_in[5];
    const float* W2      = (const float*)d_in[6];
    const float* b2      = (const float*)d_in[7];
    const float* W3      = (const float*)d_in[8];
    const float* Wv      = (const float*)d_in[9];

    float* A_a   = (float*)d_out;                    // [NN][32]
    float* out_v = (float*)d_out + (size_t)NN * DA;  // [NN][32][3]

    // new-path ws: rec[NE*4] | emb16[NN*16] | counts[NN] | offsets[NN+1] | rank[NE] | bsum[256]
    const size_t need_new = ((size_t)NE*4 + (size_t)NN*16 + NN + NN + 1 + NE + 256) * sizeof(int);
    const size_t need_leg = ((size_t)NN + NN + 1 + NE + NE) * sizeof(int);

    if (ws_size >= need_new) {
        uint4*    rec     = (uint4*)d_ws;
        unsigned* emb16   = (unsigned*)(rec + NE);
        int*      counts  = (int*)(emb16 + (size_t)NN*16);
        int*      offsets = counts + NN;
        int*      rank    = offsets + NN + 1;
        int*      bsum    = rank + NE;

        k_init    <<<1024, 256, 0, stream>>>((uint4*)d_out, (uint4*)counts);
        k_hist_emb<<<HIST_BLOCKS + EMB_BLOCKS, 256, 0, stream>>>(src, counts, rank, res_emb, emb16);
        k_scanA   <<<SCAN_BLOCKS, 256, 0, stream>>>(counts, bsum);
        k_scanC   <<<SCAN_BLOCKS, 256, 0, stream>>>(counts, bsum, offsets);
        k_prep    <<<NE / 256, 256, 0, stream>>>(r_ij, src, dst, offsets, rank, rec);
        dt_window <<<NE / 512, 256, 0, stream>>>(rec, emb16, W1, b1, W2, b2, W3, A_a, out_v);
        dt_node   <<<(NN * DA) / 256, 256, 0, stream>>>(Wv, out_v);
    } else if (ws_size >= need_leg) {
        int* counts   = (int*)d_ws;
        int* offsets  = counts + NN;
        int* rank     = offsets + NN + 1;
        int* edge_ids = rank + NE;

        hipMemsetAsync(d_out, 0, (size_t)out_size * sizeof(float), stream);
        hipMemsetAsync(counts, 0, (size_t)NN * sizeof(int), stream);
        k_hist_legacy   <<<NE / 256, 256, 0, stream>>>(src, counts, rank);
        k_scan_legacy   <<<1, 256, 0, stream>>>(counts, offsets);
        k_scatter_legacy<<<NE / 256, 256, 0, stream>>>(src, offsets, rank, edge_ids);
        dt_window_legacy<<<NE / 256, 256, 0, stream>>>(r_ij, res_emb, src, dst, edge_ids,
                                                       W1, b1, W2, b2, W3, A_a, out_v);
        dt_node         <<<(NN * DA) / 256, 256, 0, stream>>>(Wv, out_v);
    }
}

// Round 16
// 218.480 us; speedup vs baseline: 1.1906x; 1.0617x over previous
//
#include <hip/hip_runtime.h>
#include <math.h>

// DisplacementTensors: per-edge radial-MLP + segment-sum to nodes + per-node linear map.
// N_NODES=50000, N_EDGES=1600000, DIM_A=DIM_V=32, R0=5, LEAK=0.1
//
// Round 16: r15's bf16-rad LDS shrink NaN'd (cause not localizable) -> revert
// dt_window to the r14-proven f32 layout. New lever: dt_window issues ~8M
// device-scope atomics in 94us (~35/cycle chip-wide ~ TCC atomic ceiling;
// explains why occupancy/VALU levers were all null). CSR node runs are
// contiguous, so segments flushed MID-window are exclusively owned by this
// wave -> flush them with PLAIN STORES (output pre-zeroed); only the first
// segment (may span backward) and the final flush (spans forward) keep
// atomics. ~8M atomics -> ~3.2M atomics + 4.8M stores. Chain frozen from r14.
//
// d_out layout: A_a [50000*32] floats, then out_v [50000*32*3] floats.
// ws (new path, ~36MB): rec u32[NE*4] | emb16 u32[NN*16] | counts[NN] |
//                       offsets[NN+1] | rank[NE] | bsum[256]

#define NN 50000
#define NE 1600000
#define DA 32
#define PI_R0 0.62831853071795864769f  // pi / 5
#define SCAN_BLOCKS 196                // ceil(NN/256)
#define HIST_BLOCKS (NE/256)           // 6250
#define EMB_BLOCKS  ((NN*16)/256)      // 3125
#define RSTRIDE 34                     // xrad row stride in floats (136B, b64-aligned)
#define OUTQ4 1600000                  // d_out as uint4: 6.4M floats / 4
#define CNTQ4 12500                    // counts as uint4: 50000 ints / 4

typedef float v2f __attribute__((ext_vector_type(2)));
typedef short bf16x8 __attribute__((ext_vector_type(8)));   // 8 bf16 = 4 VGPRs
typedef float f32x16 __attribute__((ext_vector_type(16)));  // MFMA C/D

union frag_u { unsigned u[4]; bf16x8 v; };

__device__ __forceinline__ void wsync() {
    // intra-wave LDS handoff: wave is lockstep; drain the DS queue.
    asm volatile("s_waitcnt lgkmcnt(0)" ::: "memory");
}

__device__ __forceinline__ unsigned cvt_pk(float lo, float hi) {
    unsigned r;
    asm("v_cvt_pk_bf16_f32 %0, %1, %2" : "=v"(r) : "v"(lo), "v"(hi));
    return r;   // lo -> low 16, hi -> high 16
}

__device__ __forceinline__ float leaky(float x) {
    return fmaxf(x, 0.0f) + 0.1f * fminf(x, 0.0f);
}

// round-to-nearest-ish bf16 (add half-ulp then truncate)
__device__ __forceinline__ unsigned bf_hi(float x) {
    return (__float_as_uint(x) + 0x8000u) >> 16;
}
__device__ __forceinline__ unsigned bf_pack2(float lo, float hi) {
    return bf_hi(lo) | ((__float_as_uint(hi) + 0x8000u) & 0xffff0000u);
}

// ---------------- init: zero d_out (6.4M floats = 1.6M uint4) + counts ----------------

__global__ __launch_bounds__(256) void k_init(uint4* __restrict__ outq,
                                              uint4* __restrict__ cntq) {
    const uint4 z = make_uint4(0, 0, 0, 0);
    const int stride = gridDim.x * 256;
    for (int i = blockIdx.x * 256 + threadIdx.x; i < OUTQ4 + CNTQ4; i += stride) {
        if (i < OUTQ4) outq[i] = z;
        else           cntq[i - OUTQ4] = z;
    }
}

// ---------------- hist + embcvt fused (disjoint block ranges) ----------------

__global__ __launch_bounds__(256) void k_hist_emb(const int* __restrict__ src,
                                                  int* __restrict__ counts,
                                                  int* __restrict__ rank,
                                                  const float* __restrict__ emb,
                                                  unsigned* __restrict__ emb16) {
    const int b = blockIdx.x;
    if (b < HIST_BLOCKS) {
        const int e = b * 256 + threadIdx.x;
        rank[e] = atomicAdd(&counts[src[e]], 1);
    } else {
        const int t = (b - HIST_BLOCKS) * 256 + threadIdx.x;   // < NN*16 exactly
        emb16[t] = bf_pack2(emb[2*t], emb[2*t + 1]);
    }
}

// ---------------- scan: per-block reduce, then scanC with inline base ----------------

__global__ __launch_bounds__(256) void k_scanA(const int* __restrict__ counts,
                                               int* __restrict__ bsum) {
    __shared__ int red[256];
    const int t = threadIdx.x;
    const int idx = blockIdx.x * 256 + t;
    red[t] = (idx < NN) ? counts[idx] : 0;
    __syncthreads();
    #pragma unroll
    for (int off = 128; off > 0; off >>= 1) {
        if (t < off) red[t] += red[t + off];
        __syncthreads();
    }
    if (t == 0) bsum[blockIdx.x] = red[0];
}

__global__ __launch_bounds__(256) void k_scanC(const int* __restrict__ counts,
                                               const int* __restrict__ bsum,
                                               int* __restrict__ offsets) {
    __shared__ int sb[256];
    __shared__ int s[256];
    const int t = threadIdx.x;

    // inline block-base: inclusive scan of bsum[0..195]
    const int bv = (t < SCAN_BLOCKS) ? bsum[t] : 0;
    sb[t] = bv;
    __syncthreads();
    #pragma unroll
    for (int off = 1; off < 256; off <<= 1) {
        const int x = sb[t] + ((t >= off) ? sb[t - off] : 0);
        __syncthreads();
        sb[t] = x;
        __syncthreads();
    }
    const int base = (blockIdx.x > 0) ? sb[blockIdx.x - 1] : 0;

    // local scan of this block's counts
    const int idx = blockIdx.x * 256 + t;
    const int v = (idx < NN) ? counts[idx] : 0;
    s[t] = v;
    __syncthreads();
    #pragma unroll
    for (int off = 1; off < 256; off <<= 1) {
        const int x = s[t] + ((t >= off) ? s[t - off] : 0);
        __syncthreads();
        s[t] = x;
        __syncthreads();
    }
    const int excl = s[t] - v + base;
    if (idx < NN) offsets[idx] = excl;
    if (idx == NN - 1) offsets[NN] = excl + v;   // == NE
}

// scatter + per-edge precompute: sequential reads, random fire-and-forget writes.
// rec = {dist f32, vx|vy bf16x2, vz bf16, src u16 | dst u16 << 16}
__global__ __launch_bounds__(256) void k_prep(
    const float* __restrict__ r_ij,
    const int*   __restrict__ src,
    const int*   __restrict__ dst,
    const int*   __restrict__ offsets,
    const int*   __restrict__ rank,
    uint4* __restrict__ rec)
{
    const int e = blockIdx.x * 256 + threadIdx.x;   // grid exactly NE/256
    const int s = src[e];
    const int slot = offsets[s] + rank[e];

    const float rx = r_ij[(size_t)e*3 + 0];
    const float ry = r_ij[(size_t)e*3 + 1];
    const float rz = r_ij[(size_t)e*3 + 2];
    const float dist = sqrtf(rx*rx + ry*ry + rz*rz);

    const float nq = 1.4f * dist;
    const float e2 = __expf(2.0f * nq);
    const float sc14 = (nq > 0.0f)
        ? 1.4f * (e2 - 1.0f) * __builtin_amdgcn_rcpf((e2 + 1.0f) * nq)
        : 0.0f;

    uint4 r;
    r.x = __float_as_uint(dist);
    r.y = bf_pack2(rx * sc14, ry * sc14);
    r.z = bf_hi(rz * sc14);
    r.w = (unsigned)s | ((unsigned)dst[e] << 16);   // both < 65536
    rec[slot] = r;
}

// ---------------- phase A: MFMA MLP over CSR windows + segmented flush ----------------
// block = 256 = 4 waves; wave owns 128 contiguous CSR slots, processed as
// 2 batches of 64. Per batch: 12x mfma_f32_32x32x16_bf16 (k-slot labeling
// k(g,j)=4g+(j&3)+8*(j>>2) chains layer L's D regs into layer L+1's B frag),
// then a serial segmented reduce with PERSISTENT cur/accumulators.
// Flush policy: first segment (may span backward) + final flush (spans
// forward) use atomics; interior segments are wave-exclusive -> plain stores.

__global__ __launch_bounds__(256, 2) void dt_window(
    const uint4*    __restrict__ rec,
    const unsigned* __restrict__ emb16,
    const float* __restrict__ W1, const float* __restrict__ b1,
    const float* __restrict__ W2, const float* __restrict__ b2,
    const float* __restrict__ W3,
    float* __restrict__ A_a,    // [NN][32]  (accumulates, pre-zeroed)
    float* __restrict__ out_v)  // [NN][32][3] (accumulates raw A_v, pre-zeroed)
{
    // rows are 136B: b64-aligned; banks (34*row + col) % 32 = (2*row + col) % 32
    __shared__ float  xrad[4][64][RSTRIDE];   // [wave][edge][dim(+pad)]
    __shared__ float4 rvn_lds[4][64];         // [wave][slot] = (vx, vy, vz, bits(node))

    const int tid   = threadIdx.x;
    const int wv    = tid >> 6;
    const int lane  = tid & 63;
    const int g     = lane >> 5;          // k-group / lane half
    const int m     = lane & 31;          // row (A) / col (B) within tile
    const int wbase = blockIdx.x * 512 + wv * 128;   // grid exactly NE/512

    // ---- W fragments, loaded once: wf[layer][kt], A-slot j holds W[m][k(g,j)+16kt] ----
    frag_u wf1[2], wf2[2], wf3[2];
    #pragma unroll
    for (int kt = 0; kt < 2; ++kt) {
        const float4 a1 = *(const float4*)&W1[m*DA + 16*kt + 4*g];
        const float4 c1 = *(const float4*)&W1[m*DA + 16*kt + 8 + 4*g];
        wf1[kt].u[0] = cvt_pk(a1.x, a1.y); wf1[kt].u[1] = cvt_pk(a1.z, a1.w);
        wf1[kt].u[2] = cvt_pk(c1.x, c1.y); wf1[kt].u[3] = cvt_pk(c1.z, c1.w);
        const float4 a2 = *(const float4*)&W2[m*DA + 16*kt + 4*g];
        const float4 c2 = *(const float4*)&W2[m*DA + 16*kt + 8 + 4*g];
        wf2[kt].u[0] = cvt_pk(a2.x, a2.y); wf2[kt].u[1] = cvt_pk(a2.z, a2.w);
        wf2[kt].u[2] = cvt_pk(c2.x, c2.y); wf2[kt].u[3] = cvt_pk(c2.z, c2.w);
        const float4 a3 = *(const float4*)&W3[m*DA + 16*kt + 4*g];
        const float4 c3 = *(const float4*)&W3[m*DA + 16*kt + 8 + 4*g];
        wf3[kt].u[0] = cvt_pk(a3.x, a3.y); wf3[kt].u[1] = cvt_pk(a3.z, a3.w);
        wf3[kt].u[2] = cvt_pk(c3.x, c3.y); wf3[kt].u[3] = cvt_pk(c3.z, c3.w);
    }

    // bias per D-reg r: dim d(r,g) = (r&3) + 8*(r>>2) + 4g
    const float4 b1q0 = *(const float4*)&b1[4*g];
    const float4 b1q1 = *(const float4*)&b1[8 + 4*g];
    const float4 b1q2 = *(const float4*)&b1[16 + 4*g];
    const float4 b1q3 = *(const float4*)&b1[24 + 4*g];
    const float4 b2q0 = *(const float4*)&b2[4*g];
    const float4 b2q1 = *(const float4*)&b2[8 + 4*g];
    const float4 b2q2 = *(const float4*)&b2[16 + 4*g];
    const float4 b2q3 = *(const float4*)&b2[24 + 4*g];

    const int p = g;
    const int i = m;
    float accA = 0.0f, a0 = 0.0f, a1 = 0.0f, a2 = 0.0f;
    int cur = -1;        // sentinel; node ids >= 0
    bool firstSeg = true;   // first flushed segment may span backward -> atomic

    #pragma unroll
    for (int b = 0; b < 2; ++b) {
        const int slot = wbase + b*64 + lane;

        // ---- per-edge input: radial encode + bf16 emb gather ----
        const uint4 rc = rec[slot];                // sequential b128
        const float dist = __uint_as_float(rc.x);
        const float vx = __uint_as_float(rc.y << 16);
        const float vy = __uint_as_float(rc.y & 0xffff0000u);
        const float vz = __uint_as_float(rc.z << 16);
        const int  node = (int)(rc.w & 0xffffu);
        const int  dn   = (int)(rc.w >> 16);

        v2f xa[16];
        #pragma unroll
        for (int mm = 0; mm < 8; ++mm) {
            float sph, cph;
            __sincosf(PI_R0 * (float)(mm + 1) * dist, &sph, &cph);
            xa[mm]     = (v2f){cph, cph};
            xa[8 + mm] = (v2f){sph, sph};
        }
        const uint4* ep = (const uint4*)(emb16 + (size_t)dn * 16);
        #pragma unroll
        for (int q = 0; q < 4; ++q) {
            const uint4 u = ep[q];
            xa[q*4 + 0] += (v2f){__uint_as_float(u.x << 16), __uint_as_float(u.x & 0xffff0000u)};
            xa[q*4 + 1] += (v2f){__uint_as_float(u.y << 16), __uint_as_float(u.y & 0xffff0000u)};
            xa[q*4 + 2] += (v2f){__uint_as_float(u.z << 16), __uint_as_float(u.z & 0xffff0000u)};
            xa[q*4 + 3] += (v2f){__uint_as_float(u.w << 16), __uint_as_float(u.w & 0xffff0000u)};
        }

        rvn_lds[wv][lane] = make_float4(vx, vy, vz, __int_as_float(node));

        // pack x to bf16 pairs and stash (8 x b64)
        {
            uint2* xr = (uint2*)&xrad[wv][lane][0];
            xr[0] = make_uint2(cvt_pk(xa[0].x,  xa[0].y),  cvt_pk(xa[1].x,  xa[1].y));
            xr[1] = make_uint2(cvt_pk(xa[2].x,  xa[2].y),  cvt_pk(xa[3].x,  xa[3].y));
            xr[2] = make_uint2(cvt_pk(xa[4].x,  xa[4].y),  cvt_pk(xa[5].x,  xa[5].y));
            xr[3] = make_uint2(cvt_pk(xa[6].x,  xa[6].y),  cvt_pk(xa[7].x,  xa[7].y));
            xr[4] = make_uint2(cvt_pk(xa[8].x,  xa[8].y),  cvt_pk(xa[9].x,  xa[9].y));
            xr[5] = make_uint2(cvt_pk(xa[10].x, xa[10].y), cvt_pk(xa[11].x, xa[11].y));
            xr[6] = make_uint2(cvt_pk(xa[12].x, xa[12].y), cvt_pk(xa[13].x, xa[13].y));
            xr[7] = make_uint2(cvt_pk(xa[14].x, xa[14].y), cvt_pk(xa[15].x, xa[15].y));
        }
        wsync();

        // ---- first-layer B fragments: B-slot j of tile t holds x[edge 32t+m][k(g,j)+16kt] ----
        frag_u xf[2][2];
        #pragma unroll
        for (int t = 0; t < 2; ++t) {
            const unsigned* er = (const unsigned*)&xrad[wv][32*t + m][0];
            #pragma unroll
            for (int kt = 0; kt < 2; ++kt) {
                const uint2 qa = *(const uint2*)&er[8*kt + 2*g];
                const uint2 qb = *(const uint2*)&er[8*kt + 4 + 2*g];
                xf[t][kt].u[0] = qa.x; xf[t][kt].u[1] = qa.y;
                xf[t][kt].u[2] = qb.x; xf[t][kt].u[3] = qb.y;
            }
        }

        // ---- layer 1 ----
        f32x16 acc0, acc1;
        acc0[0]=b1q0.x; acc0[1]=b1q0.y; acc0[2]=b1q0.z; acc0[3]=b1q0.w;
        acc0[4]=b1q1.x; acc0[5]=b1q1.y; acc0[6]=b1q1.z; acc0[7]=b1q1.w;
        acc0[8]=b1q2.x; acc0[9]=b1q2.y; acc0[10]=b1q2.z; acc0[11]=b1q2.w;
        acc0[12]=b1q3.x; acc0[13]=b1q3.y; acc0[14]=b1q3.z; acc0[15]=b1q3.w;
        acc1 = acc0;
        acc0 = __builtin_amdgcn_mfma_f32_32x32x16_bf16(wf1[0].v, xf[0][0].v, acc0, 0, 0, 0);
        acc0 = __builtin_amdgcn_mfma_f32_32x32x16_bf16(wf1[1].v, xf[0][1].v, acc0, 0, 0, 0);
        acc1 = __builtin_amdgcn_mfma_f32_32x32x16_bf16(wf1[0].v, xf[1][0].v, acc1, 0, 0, 0);
        acc1 = __builtin_amdgcn_mfma_f32_32x32x16_bf16(wf1[1].v, xf[1][1].v, acc1, 0, 0, 0);

        frag_u hf[2][2];
        #pragma unroll
        for (int t = 0; t < 2; ++t) {
            const f32x16 a = t ? acc1 : acc0;
            float h[16];
            #pragma unroll
            for (int r = 0; r < 16; ++r) h[r] = leaky(a[r]);
            hf[t][0].u[0] = cvt_pk(h[0], h[1]);   hf[t][0].u[1] = cvt_pk(h[2], h[3]);
            hf[t][0].u[2] = cvt_pk(h[4], h[5]);   hf[t][0].u[3] = cvt_pk(h[6], h[7]);
            hf[t][1].u[0] = cvt_pk(h[8], h[9]);   hf[t][1].u[1] = cvt_pk(h[10], h[11]);
            hf[t][1].u[2] = cvt_pk(h[12], h[13]); hf[t][1].u[3] = cvt_pk(h[14], h[15]);
        }

        // ---- layer 2 ----
        f32x16 c0, c1;
        c0[0]=b2q0.x; c0[1]=b2q0.y; c0[2]=b2q0.z; c0[3]=b2q0.w;
        c0[4]=b2q1.x; c0[5]=b2q1.y; c0[6]=b2q1.z; c0[7]=b2q1.w;
        c0[8]=b2q2.x; c0[9]=b2q2.y; c0[10]=b2q2.z; c0[11]=b2q2.w;
        c0[12]=b2q3.x; c0[13]=b2q3.y; c0[14]=b2q3.z; c0[15]=b2q3.w;
        c1 = c0;
        c0 = __builtin_amdgcn_mfma_f32_32x32x16_bf16(wf2[0].v, hf[0][0].v, c0, 0, 0, 0);
        c0 = __builtin_amdgcn_mfma_f32_32x32x16_bf16(wf2[1].v, hf[0][1].v, c0, 0, 0, 0);
        c1 = __builtin_amdgcn_mfma_f32_32x32x16_bf16(wf2[0].v, hf[1][0].v, c1, 0, 0, 0);
        c1 = __builtin_amdgcn_mfma_f32_32x32x16_bf16(wf2[1].v, hf[1][1].v, c1, 0, 0, 0);

        frag_u gf[2][2];
        #pragma unroll
        for (int t = 0; t < 2; ++t) {
            const f32x16 a = t ? c1 : c0;
            float h[16];
            #pragma unroll
            for (int r = 0; r < 16; ++r) h[r] = leaky(a[r]);
            gf[t][0].u[0] = cvt_pk(h[0], h[1]);   gf[t][0].u[1] = cvt_pk(h[2], h[3]);
            gf[t][0].u[2] = cvt_pk(h[4], h[5]);   gf[t][0].u[3] = cvt_pk(h[6], h[7]);
            gf[t][1].u[0] = cvt_pk(h[8], h[9]);   gf[t][1].u[1] = cvt_pk(h[10], h[11]);
            gf[t][1].u[2] = cvt_pk(h[12], h[13]); gf[t][1].u[3] = cvt_pk(h[14], h[15]);
        }

        // ---- layer 3 (no bias, no activation) ----
        f32x16 r0 = {}, r1 = {};
        r0 = __builtin_amdgcn_mfma_f32_32x32x16_bf16(wf3[0].v, gf[0][0].v, r0, 0, 0, 0);
        r0 = __builtin_amdgcn_mfma_f32_32x32x16_bf16(wf3[1].v, gf[0][1].v, r0, 0, 0, 0);
        r1 = __builtin_amdgcn_mfma_f32_32x32x16_bf16(wf3[0].v, gf[1][0].v, r1, 0, 0, 0);
        r1 = __builtin_amdgcn_mfma_f32_32x32x16_bf16(wf3[1].v, gf[1][1].v, r1, 0, 0, 0);

        // ---- write rad back (b64 stores) ----
        #pragma unroll
        for (int t = 0; t < 2; ++t) {
            const f32x16 a = t ? r1 : r0;
            float* rr = &xrad[wv][32*t + m][0];
            *(float2*)&rr[4*g]          = make_float2(a[0],  a[1]);
            *(float2*)&rr[4*g + 2]      = make_float2(a[2],  a[3]);
            *(float2*)&rr[8 + 4*g]      = make_float2(a[4],  a[5]);
            *(float2*)&rr[8 + 4*g + 2]  = make_float2(a[6],  a[7]);
            *(float2*)&rr[16 + 4*g]     = make_float2(a[8],  a[9]);
            *(float2*)&rr[16 + 4*g + 2] = make_float2(a[10], a[11]);
            *(float2*)&rr[24 + 4*g]     = make_float2(a[12], a[13]);
            *(float2*)&rr[24 + 4*g + 2] = make_float2(a[14], a[15]);
        }
        wsync();

        // ---- serial segmented reduce (persistent cur/firstSeg across batches) ----
        #pragma unroll 4
        for (int l = 0; l < 64; ++l) {
            const float4 rvn = rvn_lds[wv][l];          // uniform b128 broadcast
            const int nd = __float_as_int(rvn.w);       // wave-uniform
            const float rd = xrad[wv][l][i];
            if (nd != cur) {                            // wave-uniform branch
                if (cur >= 0) {
                    if (firstSeg) {
                        // may span backward across window boundary -> atomic
                        if (p == 0) {
                            atomicAdd(&A_a[cur*DA + i], accA);
                            atomicAdd(&out_v[(cur*DA + i)*3 + 0], a0);
                        } else {
                            atomicAdd(&out_v[(cur*DA + i)*3 + 1], a1);
                            atomicAdd(&out_v[(cur*DA + i)*3 + 2], a2);
                        }
                        firstSeg = false;
                    } else {
                        // interior segment: node's full CSR run is inside this
                        // window -> exclusively owned -> plain stores
                        if (p == 0) {
                            A_a[cur*DA + i] = accA;
                            out_v[(cur*DA + i)*3 + 0] = a0;
                        } else {
                            out_v[(cur*DA + i)*3 + 1] = a1;
                            out_v[(cur*DA + i)*3 + 2] = a2;
                        }
                    }
                }
                accA = a0 = a1 = a2 = 0.0f;
                cur = nd;
            }
            accA += rd;
            a0 += rd * rvn.x;
            a1 += rd * rvn.y;
            a2 += rd * rvn.z;
        }
        wsync();   // reduce reads retired before next batch overwrites buffers
    }

    // final flush: may span forward across window boundary -> always atomic
    if (p == 0) {
        atomicAdd(&A_a[cur*DA + i], accA);
        atomicAdd(&out_v[(cur*DA + i)*3 + 0], a0);
    } else {
        atomicAdd(&out_v[(cur*DA + i)*3 + 1], a1);
        atomicAdd(&out_v[(cur*DA + i)*3 + 2], a2);
    }
}

// ---------------- phase B: out_v[n][v][d] = sum_a Wv[v][a] * A_v[n][a][d], in place ----------------

__global__ __launch_bounds__(256) void dt_node(
    const float* __restrict__ Wv,
    float* Av_out)   // aliased read+write, deliberately NOT restrict
{
    __shared__ float sWv[DA*DA];
    for (int i = threadIdx.x; i < DA*DA; i += 256) sWv[i] = Wv[i];
    __syncthreads();

    const int t = blockIdx.x * 256 + threadIdx.x;   // grid exactly NN*32/256
    const int n = t >> 5;
    const int v = t & 31;

    const float* av = Av_out + (size_t)n * (DA*3);
    float o0 = 0.0f, o1 = 0.0f, o2 = 0.0f;
    #pragma unroll
    for (int a = 0; a < DA; ++a) {
        const float w = sWv[v*DA + a];
        o0 += w * av[a*3 + 0];
        o1 += w * av[a*3 + 1];
        o2 += w * av[a*3 + 2];
    }
    __syncthreads();   // all loads of this block's nodes complete before any store
    float* o = Av_out + (size_t)n * (DA*3) + v*3;
    o[0] = o0; o[1] = o1; o[2] = o2;
}

// ---------------- legacy path (used only if ws too small for the new path) ----------------

__global__ __launch_bounds__(256) void k_hist_legacy(const int* __restrict__ src,
                                                     int* __restrict__ counts,
                                                     int* __restrict__ rank) {
    const int e = blockIdx.x * 256 + threadIdx.x;
    rank[e] = atomicAdd(&counts[src[e]], 1);
}

__global__ __launch_bounds__(256) void k_scan_legacy(const int* __restrict__ counts,
                                                     int* __restrict__ offsets) {
    __shared__ int part[256];
    const int CH = (NN + 255) / 256;
    const int t = threadIdx.x;
    const int base = t * CH;
    int s = 0;
    for (int k = 0; k < CH; ++k) { const int idx = base + k; if (idx < NN) s += counts[idx]; }
    part[t] = s;
    __syncthreads();
    if (t == 0) {
        int run = 0;
        for (int k = 0; k < 256; ++k) { const int v = part[k]; part[k] = run; run += v; }
    }
    __syncthreads();
    int run = part[t];
    for (int k = 0; k < CH; ++k) {
        const int idx = base + k;
        if (idx < NN) { offsets[idx] = run; run += counts[idx]; }
    }
    if (t == 255) offsets[NN] = run;
}

__global__ __launch_bounds__(256) void k_scatter_legacy(const int* __restrict__ src,
                                                        const int* __restrict__ offsets,
                                                        const int* __restrict__ rank,
                                                        int* __restrict__ edge_ids) {
    const int e = blockIdx.x * 256 + threadIdx.x;
    edge_ids[offsets[src[e]] + rank[e]] = e;
}

__global__ __launch_bounds__(256, 2) void dt_window_legacy(
    const float* __restrict__ r_ij,
    const float* __restrict__ res_emb,
    const int*   __restrict__ src,
    const int*   __restrict__ dst,
    const int*   __restrict__ edge_ids,
    const float* __restrict__ W1, const float* __restrict__ b1,
    const float* __restrict__ W2, const float* __restrict__ b2,
    const float* __restrict__ W3,
    float* __restrict__ A_a,
    float* __restrict__ out_v)
{
    __shared__ float  rad_lds[4][32][36];
    __shared__ float4 rvn_lds[4][64];

    const int tid  = threadIdx.x;
    const int wv   = tid >> 6;
    const int lane = tid & 63;
    const int slot = blockIdx.x * 256 + tid;

    const int eid  = edge_ids[slot];
    const int node = src[eid];

    const float rx = r_ij[(size_t)eid*3 + 0];
    const float ry = r_ij[(size_t)eid*3 + 1];
    const float rz = r_ij[(size_t)eid*3 + 2];
    const float dist = sqrtf(rx*rx + ry*ry + rz*rz);

    float xa[DA], xb[DA];
    #pragma unroll
    for (int mm = 0; mm < 8; ++mm) {
        float sph, cph;
        __sincosf(PI_R0 * (float)(mm + 1) * dist, &sph, &cph);
        xa[2*mm] = cph; xa[2*mm+1] = cph;
        xa[16+2*mm] = sph; xa[16+2*mm+1] = sph;
    }
    const float4* er = (const float4*)(res_emb + (size_t)dst[eid] * DA);
    #pragma unroll
    for (int q = 0; q < 8; ++q) {
        const float4 v = er[q];
        xa[q*4+0] += v.x; xa[q*4+1] += v.y; xa[q*4+2] += v.z; xa[q*4+3] += v.w;
    }
    #pragma unroll
    for (int i = 0; i < DA; ++i) {
        float acc = b1[i];
        #pragma unroll
        for (int j = 0; j < DA; ++j) acc += W1[i*DA + j] * xa[j];
        xb[i] = (acc >= 0.0f) ? acc : 0.1f * acc;
    }
    #pragma unroll
    for (int i = 0; i < DA; ++i) {
        float acc = b2[i];
        #pragma unroll
        for (int j = 0; j < DA; ++j) acc += W2[i*DA + j] * xb[j];
        xa[i] = (acc >= 0.0f) ? acc : 0.1f * acc;
    }
    #pragma unroll
    for (int i = 0; i < DA; ++i) {
        float acc = 0.0f;
        #pragma unroll
        for (int j = 0; j < DA; ++j) acc += W3[i*DA + j] * xa[j];
        xb[i] = acc;
    }

    const float qx = rx*1.4f, qy = ry*1.4f, qz = rz*1.4f;
    const float nq = sqrtf(qx*qx + qy*qy + qz*qz);
    const float e2 = __expf(2.0f * nq);
    const float sc = (nq > 0.0f)
        ? (e2 - 1.0f) * __builtin_amdgcn_rcpf((e2 + 1.0f) * nq)
        : 0.0f;

    rvn_lds[wv][lane] = make_float4(qx*sc, qy*sc, qz*sc, __int_as_float(node));

    const int p = lane >> 5;
    const int i = lane & 31;

    if (lane < 32) {
        float* rrow = rad_lds[wv][lane];
        #pragma unroll
        for (int q = 0; q < 8; ++q)
            *(float4*)&rrow[q*4] = make_float4(xb[q*4+0], xb[q*4+1], xb[q*4+2], xb[q*4+3]);
    }
    wsync();

    float accA = 0.0f, a0 = 0.0f, a1 = 0.0f, a2 = 0.0f;
    int cur = __float_as_int(rvn_lds[wv][0].w);

    #pragma unroll 4
    for (int l = 0; l < 32; ++l) {
        const float4 rvn = rvn_lds[wv][l];
        const int nd = __float_as_int(rvn.w);
        const float rd = rad_lds[wv][l][i];
        if (nd != cur) {
            if (p == 0) {
                atomicAdd(&A_a[cur*DA + i], accA);
                atomicAdd(&out_v[(cur*DA + i)*3 + 0], a0);
            } else {
                atomicAdd(&out_v[(cur*DA + i)*3 + 1], a1);
                atomicAdd(&out_v[(cur*DA + i)*3 + 2], a2);
            }
            accA = a0 = a1 = a2 = 0.0f;
            cur = nd;
        }
        accA += rd; a0 += rd*rvn.x; a1 += rd*rvn.y; a2 += rd*rvn.z;
    }
    wsync();
    if (lane >= 32) {
        float* rrow = rad_lds[wv][lane - 32];
        #pragma unroll
        for (int q = 0; q < 8; ++q)
            *(float4*)&rrow[q*4] = make_float4(xb[q*4+0], xb[q*4+1], xb[q*4+2], xb[q*4+3]);
    }
    wsync();
    #pragma unroll 4
    for (int l = 32; l < 64; ++l) {
        const float4 rvn = rvn_lds[wv][l];
        const int nd = __float_as_int(rvn.w);
        const float rd = rad_lds[wv][l - 32][i];
        if (nd != cur) {
            if (p == 0) {
                atomicAdd(&A_a[cur*DA + i], accA);
                atomicAdd(&out_v[(cur*DA + i)*3 + 0], a0);
            } else {
                atomicAdd(&out_v[(cur*DA + i)*3 + 1], a1);
                atomicAdd(&out_v[(cur*DA + i)*3 + 2], a2);
            }
            accA = a0 = a1 = a2 = 0.0f;
            cur = nd;
        }
        accA += rd; a0 += rd*rvn.x; a1 += rd*rvn.y; a2 += rd*rvn.z;
    }
    if (p == 0) {
        atomicAdd(&A_a[cur*DA + i], accA);
        atomicAdd(&out_v[(cur*DA + i)*3 + 0], a0);
    } else {
        atomicAdd(&out_v[(cur*DA + i)*3 + 1], a1);
        atomicAdd(&out_v[(cur*DA + i)*3 + 2], a2);
    }
}

// ---------------- launch ----------------

extern "C" void kernel_launch(void* const* d_in, const int* in_sizes, int n_in,
                              void* d_out, int out_size, void* d_ws, size_t ws_size,
                              hipStream_t stream) {
    const float* r_ij    = (const float*)d_in[0];
    const float* res_emb = (const float*)d_in[1];
    const int*   src     = (const int*)d_in[2];
    const int*   dst     = (const int*)d_in[3];
    const float* W1      = (const float*)d_in[4];
    const float* b1      = (const float*)d_in[5];
    const float* W2      = (const float*)d_in[6];
    const float* b2      = (const float*)d_in[7];
    const float* W3      = (const float*)d_in[8];
    const float* Wv      = (const float*)d_in[9];

    float* A_a   = (float*)d_out;                    // [NN][32]
    float* out_v = (float*)d_out + (size_t)NN * DA;  // [NN][32][3]

    // new-path ws: rec[NE*4] | emb16[NN*16] | counts[NN] | offsets[NN+1] | rank[NE] | bsum[256]
    const size_t need_new = ((size_t)NE*4 + (size_t)NN*16 + NN + NN + 1 + NE + 256) * sizeof(int);
    const size_t need_leg = ((size_t)NN + NN + 1 + NE + NE) * sizeof(int);

    if (ws_size >= need_new) {
        uint4*    rec     = (uint4*)d_ws;
        unsigned* emb16   = (unsigned*)(rec + NE);
        int*      counts  = (int*)(emb16 + (size_t)NN*16);
        int*      offsets = counts + NN;
        int*      rank    = offsets + NN + 1;
        int*      bsum    = rank + NE;

        k_init    <<<1024, 256, 0, stream>>>((uint4*)d_out, (uint4*)counts);
        k_hist_emb<<<HIST_BLOCKS + EMB_BLOCKS, 256, 0, stream>>>(src, counts, rank, res_emb, emb16);
        k_scanA   <<<SCAN_BLOCKS, 256, 0, stream>>>(counts, bsum);
        k_scanC   <<<SCAN_BLOCKS, 256, 0, stream>>>(counts, bsum, offsets);
        k_prep    <<<NE / 256, 256, 0, stream>>>(r_ij, src, dst, offsets, rank, rec);
        dt_window <<<NE / 512, 256, 0, stream>>>(rec, emb16, W1, b1, W2, b2, W3, A_a, out_v);
        dt_node   <<<(NN * DA) / 256, 256, 0, stream>>>(Wv, out_v);
    } else if (ws_size >= need_leg) {
        int* counts   = (int*)d_ws;
        int* offsets  = counts + NN;
        int* rank     = offsets + NN + 1;
        int* edge_ids = rank + NE;

        hipMemsetAsync(d_out, 0, (size_t)out_size * sizeof(float), stream);
        hipMemsetAsync(counts, 0, (size_t)NN * sizeof(int), stream);
        k_hist_legacy   <<<NE / 256, 256, 0, stream>>>(src, counts, rank);
        k_scan_legacy   <<<1, 256, 0, stream>>>(counts, offsets);
        k_scatter_legacy<<<NE / 256, 256, 0, stream>>>(src, offsets, rank, edge_ids);
        dt_window_legacy<<<NE / 256, 256, 0, stream>>>(r_ij, res_emb, src, dst, edge_ids,
                                                       W1, b1, W2, b2, W3, A_a, out_v);
        dt_node         <<<(NN * DA) / 256, 256, 0, stream>>>(Wv, out_v);
    }
}

// Round 17
// 214.101 us; speedup vs baseline: 1.2149x; 1.0205x over previous
//
#include <hip/hip_runtime.h>
#include <math.h>

// DisplacementTensors: per-edge radial-MLP + segment-sum to nodes + per-node linear map.
// N_NODES=50000, N_EDGES=1600000, DIM_A=DIM_V=32, R0=5, LEAK=0.1
//
// Round 17: r16 confirmed dt_window's atomic wall (interior plain stores:
// 94->85.7us, WRITE 77.7->49.8MB). Chain (~125us) now dominated by k_hist's
// 1.6M returning atomics at 32-way contention. Retry sub-binning WITHOUT
// r12's scan blowup: 4-way bins (200K, ~8-way contention) scanned by the
// ORIGINAL 196-block scans -- each scan thread owns one node's 4 adjacent
// sub-bins in-register (uint4 load). Node runs stay contiguous; edge order
// within a node permutes (reduce is order-agnostic).
// dt_window + dt_node FROZEN from r16 (control).
//
// d_out layout: A_a [50000*32] floats, then out_v [50000*32*3] floats.
// ws (new path, ~37MB): rec u32[NE*4] | emb16 u32[NN*16] | counts[NB] |
//                       offsets[NB] | rank[NE] | bsum[256]

#define NN 50000
#define NE 1600000
#define DA 32
#define NB (NN*4)                      // 4-way sub-binned histogram
#define PI_R0 0.62831853071795864769f  // pi / 5
#define SCAN_BLOCKS 196                // ceil(NN/256): one thread per NODE
#define HIST_BLOCKS (NE/256)           // 6250
#define EMB_BLOCKS  ((NN*16)/256)      // 3125
#define RSTRIDE 34                     // xrad row stride in floats (136B, b64-aligned)
#define OUTQ4 1600000                  // d_out as uint4: 6.4M floats / 4
#define CNTQ4 50000                    // counts as uint4: 200000 ints / 4

typedef float v2f __attribute__((ext_vector_type(2)));
typedef short bf16x8 __attribute__((ext_vector_type(8)));   // 8 bf16 = 4 VGPRs
typedef float f32x16 __attribute__((ext_vector_type(16)));  // MFMA C/D

union frag_u { unsigned u[4]; bf16x8 v; };

__device__ __forceinline__ void wsync() {
    // intra-wave LDS handoff: wave is lockstep; drain the DS queue.
    asm volatile("s_waitcnt lgkmcnt(0)" ::: "memory");
}

__device__ __forceinline__ unsigned cvt_pk(float lo, float hi) {
    unsigned r;
    asm("v_cvt_pk_bf16_f32 %0, %1, %2" : "=v"(r) : "v"(lo), "v"(hi));
    return r;   // lo -> low 16, hi -> high 16
}

__device__ __forceinline__ float leaky(float x) {
    return fmaxf(x, 0.0f) + 0.1f * fminf(x, 0.0f);
}

// round-to-nearest-ish bf16 (add half-ulp then truncate)
__device__ __forceinline__ unsigned bf_hi(float x) {
    return (__float_as_uint(x) + 0x8000u) >> 16;
}
__device__ __forceinline__ unsigned bf_pack2(float lo, float hi) {
    return bf_hi(lo) | ((__float_as_uint(hi) + 0x8000u) & 0xffff0000u);
}

// ---------------- init: zero d_out (1.6M uint4) + counts (50K uint4) ----------------

__global__ __launch_bounds__(256) void k_init(uint4* __restrict__ outq,
                                              uint4* __restrict__ cntq) {
    const uint4 z = make_uint4(0, 0, 0, 0);
    const int stride = gridDim.x * 256;
    for (int i = blockIdx.x * 256 + threadIdx.x; i < OUTQ4 + CNTQ4; i += stride) {
        if (i < OUTQ4) outq[i] = z;
        else           cntq[i - OUTQ4] = z;
    }
}

// ---------------- hist (4-way sub-binned) + embcvt fused ----------------

__global__ __launch_bounds__(256) void k_hist_emb(const int* __restrict__ src,
                                                  int* __restrict__ counts,
                                                  int* __restrict__ rank,
                                                  const float* __restrict__ emb,
                                                  unsigned* __restrict__ emb16) {
    const int b = blockIdx.x;
    if (b < HIST_BLOCKS) {
        const int e = b * 256 + threadIdx.x;
        const int key = (src[e] << 2) | (e & 3);   // ~8 edges/bin
        rank[e] = atomicAdd(&counts[key], 1);
    } else {
        const int t = (b - HIST_BLOCKS) * 256 + threadIdx.x;   // < NN*16 exactly
        emb16[t] = bf_pack2(emb[2*t], emb[2*t + 1]);
    }
}

// ---------------- scan over nodes; each thread folds its node's 4 sub-bins ----------------

__global__ __launch_bounds__(256) void k_scanA(const uint4* __restrict__ cnt4,   // counts as uint4[NN]
                                               int* __restrict__ bsum) {
    __shared__ int red[256];
    const int t = threadIdx.x;
    const int idx = blockIdx.x * 256 + t;
    int v = 0;
    if (idx < NN) {
        const uint4 c = cnt4[idx];
        v = (int)(c.x + c.y + c.z + c.w);
    }
    red[t] = v;
    __syncthreads();
    #pragma unroll
    for (int off = 128; off > 0; off >>= 1) {
        if (t < off) red[t] += red[t + off];
        __syncthreads();
    }
    if (t == 0) bsum[blockIdx.x] = red[0];
}

__global__ __launch_bounds__(256) void k_scanC(const uint4* __restrict__ cnt4,
                                               const int* __restrict__ bsum,
                                               uint4* __restrict__ offs4) {   // offsets as uint4[NN]
    __shared__ int sb[256];
    __shared__ int s[256];
    const int t = threadIdx.x;

    // inline block-base: inclusive scan of bsum[0..195]
    const int bv = (t < SCAN_BLOCKS) ? bsum[t] : 0;
    sb[t] = bv;
    __syncthreads();
    #pragma unroll
    for (int off = 1; off < 256; off <<= 1) {
        const int x = sb[t] + ((t >= off) ? sb[t - off] : 0);
        __syncthreads();
        sb[t] = x;
        __syncthreads();
    }
    const int base = (blockIdx.x > 0) ? sb[blockIdx.x - 1] : 0;

    // local scan of this block's node totals
    const int idx = blockIdx.x * 256 + t;
    uint4 c = make_uint4(0, 0, 0, 0);
    if (idx < NN) c = cnt4[idx];
    const int v = (int)(c.x + c.y + c.z + c.w);
    s[t] = v;
    __syncthreads();
    #pragma unroll
    for (int off = 1; off < 256; off <<= 1) {
        const int x = s[t] + ((t >= off) ? s[t - off] : 0);
        __syncthreads();
        s[t] = x;
        __syncthreads();
    }
    if (idx < NN) {
        const unsigned excl = (unsigned)(s[t] - v + base);
        offs4[idx] = make_uint4(excl,
                                excl + c.x,
                                excl + c.x + c.y,
                                excl + c.x + c.y + c.z);
    }
}

// scatter + per-edge precompute: sequential reads, random fire-and-forget writes.
// rec = {dist f32, vx|vy bf16x2, vz bf16, src u16 | dst u16 << 16}
__global__ __launch_bounds__(256) void k_prep(
    const float* __restrict__ r_ij,
    const int*   __restrict__ src,
    const int*   __restrict__ dst,
    const int*   __restrict__ offsets,   // [NB]
    const int*   __restrict__ rank,
    uint4* __restrict__ rec)
{
    const int e = blockIdx.x * 256 + threadIdx.x;   // grid exactly NE/256
    const int s = src[e];
    const int slot = offsets[(s << 2) | (e & 3)] + rank[e];

    const float rx = r_ij[(size_t)e*3 + 0];
    const float ry = r_ij[(size_t)e*3 + 1];
    const float rz = r_ij[(size_t)e*3 + 2];
    const float dist = sqrtf(rx*rx + ry*ry + rz*rz);

    const float nq = 1.4f * dist;
    const float e2 = __expf(2.0f * nq);
    const float sc14 = (nq > 0.0f)
        ? 1.4f * (e2 - 1.0f) * __builtin_amdgcn_rcpf((e2 + 1.0f) * nq)
        : 0.0f;

    uint4 r;
    r.x = __float_as_uint(dist);
    r.y = bf_pack2(rx * sc14, ry * sc14);
    r.z = bf_hi(rz * sc14);
    r.w = (unsigned)s | ((unsigned)dst[e] << 16);   // both < 65536
    rec[slot] = r;
}

// ---------------- phase A: MFMA MLP over CSR windows + segmented flush ----------------
// [FROZEN from round 16 -- passing, 85.7us]

__global__ __launch_bounds__(256, 2) void dt_window(
    const uint4*    __restrict__ rec,
    const unsigned* __restrict__ emb16,
    const float* __restrict__ W1, const float* __restrict__ b1,
    const float* __restrict__ W2, const float* __restrict__ b2,
    const float* __restrict__ W3,
    float* __restrict__ A_a,    // [NN][32]  (accumulates, pre-zeroed)
    float* __restrict__ out_v)  // [NN][32][3] (accumulates raw A_v, pre-zeroed)
{
    __shared__ float  xrad[4][64][RSTRIDE];   // [wave][edge][dim(+pad)]
    __shared__ float4 rvn_lds[4][64];         // [wave][slot] = (vx, vy, vz, bits(node))

    const int tid   = threadIdx.x;
    const int wv    = tid >> 6;
    const int lane  = tid & 63;
    const int g     = lane >> 5;          // k-group / lane half
    const int m     = lane & 31;          // row (A) / col (B) within tile
    const int wbase = blockIdx.x * 512 + wv * 128;   // grid exactly NE/512

    frag_u wf1[2], wf2[2], wf3[2];
    #pragma unroll
    for (int kt = 0; kt < 2; ++kt) {
        const float4 a1 = *(const float4*)&W1[m*DA + 16*kt + 4*g];
        const float4 c1 = *(const float4*)&W1[m*DA + 16*kt + 8 + 4*g];
        wf1[kt].u[0] = cvt_pk(a1.x, a1.y); wf1[kt].u[1] = cvt_pk(a1.z, a1.w);
        wf1[kt].u[2] = cvt_pk(c1.x, c1.y); wf1[kt].u[3] = cvt_pk(c1.z, c1.w);
        const float4 a2 = *(const float4*)&W2[m*DA + 16*kt + 4*g];
        const float4 c2 = *(const float4*)&W2[m*DA + 16*kt + 8 + 4*g];
        wf2[kt].u[0] = cvt_pk(a2.x, a2.y); wf2[kt].u[1] = cvt_pk(a2.z, a2.w);
        wf2[kt].u[2] = cvt_pk(c2.x, c2.y); wf2[kt].u[3] = cvt_pk(c2.z, c2.w);
        const float4 a3 = *(const float4*)&W3[m*DA + 16*kt + 4*g];
        const float4 c3 = *(const float4*)&W3[m*DA + 16*kt + 8 + 4*g];
        wf3[kt].u[0] = cvt_pk(a3.x, a3.y); wf3[kt].u[1] = cvt_pk(a3.z, a3.w);
        wf3[kt].u[2] = cvt_pk(c3.x, c3.y); wf3[kt].u[3] = cvt_pk(c3.z, c3.w);
    }

    const float4 b1q0 = *(const float4*)&b1[4*g];
    const float4 b1q1 = *(const float4*)&b1[8 + 4*g];
    const float4 b1q2 = *(const float4*)&b1[16 + 4*g];
    const float4 b1q3 = *(const float4*)&b1[24 + 4*g];
    const float4 b2q0 = *(const float4*)&b2[4*g];
    const float4 b2q1 = *(const float4*)&b2[8 + 4*g];
    const float4 b2q2 = *(const float4*)&b2[16 + 4*g];
    const float4 b2q3 = *(const float4*)&b2[24 + 4*g];

    const int p = g;
    const int i = m;
    float accA = 0.0f, a0 = 0.0f, a1 = 0.0f, a2 = 0.0f;
    int cur = -1;
    bool firstSeg = true;

    #pragma unroll
    for (int b = 0; b < 2; ++b) {
        const int slot = wbase + b*64 + lane;

        const uint4 rc = rec[slot];
        const float dist = __uint_as_float(rc.x);
        const float vx = __uint_as_float(rc.y << 16);
        const float vy = __uint_as_float(rc.y & 0xffff0000u);
        const float vz = __uint_as_float(rc.z << 16);
        const int  node = (int)(rc.w & 0xffffu);
        const int  dn   = (int)(rc.w >> 16);

        v2f xa[16];
        #pragma unroll
        for (int mm = 0; mm < 8; ++mm) {
            float sph, cph;
            __sincosf(PI_R0 * (float)(mm + 1) * dist, &sph, &cph);
            xa[mm]     = (v2f){cph, cph};
            xa[8 + mm] = (v2f){sph, sph};
        }
        const uint4* ep = (const uint4*)(emb16 + (size_t)dn * 16);
        #pragma unroll
        for (int q = 0; q < 4; ++q) {
            const uint4 u = ep[q];
            xa[q*4 + 0] += (v2f){__uint_as_float(u.x << 16), __uint_as_float(u.x & 0xffff0000u)};
            xa[q*4 + 1] += (v2f){__uint_as_float(u.y << 16), __uint_as_float(u.y & 0xffff0000u)};
            xa[q*4 + 2] += (v2f){__uint_as_float(u.z << 16), __uint_as_float(u.z & 0xffff0000u)};
            xa[q*4 + 3] += (v2f){__uint_as_float(u.w << 16), __uint_as_float(u.w & 0xffff0000u)};
        }

        rvn_lds[wv][lane] = make_float4(vx, vy, vz, __int_as_float(node));

        {
            uint2* xr = (uint2*)&xrad[wv][lane][0];
            xr[0] = make_uint2(cvt_pk(xa[0].x,  xa[0].y),  cvt_pk(xa[1].x,  xa[1].y));
            xr[1] = make_uint2(cvt_pk(xa[2].x,  xa[2].y),  cvt_pk(xa[3].x,  xa[3].y));
            xr[2] = make_uint2(cvt_pk(xa[4].x,  xa[4].y),  cvt_pk(xa[5].x,  xa[5].y));
            xr[3] = make_uint2(cvt_pk(xa[6].x,  xa[6].y),  cvt_pk(xa[7].x,  xa[7].y));
            xr[4] = make_uint2(cvt_pk(xa[8].x,  xa[8].y),  cvt_pk(xa[9].x,  xa[9].y));
            xr[5] = make_uint2(cvt_pk(xa[10].x, xa[10].y), cvt_pk(xa[11].x, xa[11].y));
            xr[6] = make_uint2(cvt_pk(xa[12].x, xa[12].y), cvt_pk(xa[13].x, xa[13].y));
            xr[7] = make_uint2(cvt_pk(xa[14].x, xa[14].y), cvt_pk(xa[15].x, xa[15].y));
        }
        wsync();

        frag_u xf[2][2];
        #pragma unroll
        for (int t = 0; t < 2; ++t) {
            const unsigned* er = (const unsigned*)&xrad[wv][32*t + m][0];
            #pragma unroll
            for (int kt = 0; kt < 2; ++kt) {
                const uint2 qa = *(const uint2*)&er[8*kt + 2*g];
                const uint2 qb = *(const uint2*)&er[8*kt + 4 + 2*g];
                xf[t][kt].u[0] = qa.x; xf[t][kt].u[1] = qa.y;
                xf[t][kt].u[2] = qb.x; xf[t][kt].u[3] = qb.y;
            }
        }

        f32x16 acc0, acc1;
        acc0[0]=b1q0.x; acc0[1]=b1q0.y; acc0[2]=b1q0.z; acc0[3]=b1q0.w;
        acc0[4]=b1q1.x; acc0[5]=b1q1.y; acc0[6]=b1q1.z; acc0[7]=b1q1.w;
        acc0[8]=b1q2.x; acc0[9]=b1q2.y; acc0[10]=b1q2.z; acc0[11]=b1q2.w;
        acc0[12]=b1q3.x; acc0[13]=b1q3.y; acc0[14]=b1q3.z; acc0[15]=b1q3.w;
        acc1 = acc0;
        acc0 = __builtin_amdgcn_mfma_f32_32x32x16_bf16(wf1[0].v, xf[0][0].v, acc0, 0, 0, 0);
        acc0 = __builtin_amdgcn_mfma_f32_32x32x16_bf16(wf1[1].v, xf[0][1].v, acc0, 0, 0, 0);
        acc1 = __builtin_amdgcn_mfma_f32_32x32x16_bf16(wf1[0].v, xf[1][0].v, acc1, 0, 0, 0);
        acc1 = __builtin_amdgcn_mfma_f32_32x32x16_bf16(wf1[1].v, xf[1][1].v, acc1, 0, 0, 0);

        frag_u hf[2][2];
        #pragma unroll
        for (int t = 0; t < 2; ++t) {
            const f32x16 a = t ? acc1 : acc0;
            float h[16];
            #pragma unroll
            for (int r = 0; r < 16; ++r) h[r] = leaky(a[r]);
            hf[t][0].u[0] = cvt_pk(h[0], h[1]);   hf[t][0].u[1] = cvt_pk(h[2], h[3]);
            hf[t][0].u[2] = cvt_pk(h[4], h[5]);   hf[t][0].u[3] = cvt_pk(h[6], h[7]);
            hf[t][1].u[0] = cvt_pk(h[8], h[9]);   hf[t][1].u[1] = cvt_pk(h[10], h[11]);
            hf[t][1].u[2] = cvt_pk(h[12], h[13]); hf[t][1].u[3] = cvt_pk(h[14], h[15]);
        }

        f32x16 c0, c1;
        c0[0]=b2q0.x; c0[1]=b2q0.y; c0[2]=b2q0.z; c0[3]=b2q0.w;
        c0[4]=b2q1.x; c0[5]=b2q1.y; c0[6]=b2q1.z; c0[7]=b2q1.w;
        c0[8]=b2q2.x; c0[9]=b2q2.y; c0[10]=b2q2.z; c0[11]=b2q2.w;
        c0[12]=b2q3.x; c0[13]=b2q3.y; c0[14]=b2q3.z; c0[15]=b2q3.w;
        c1 = c0;
        c0 = __builtin_amdgcn_mfma_f32_32x32x16_bf16(wf2[0].v, hf[0][0].v, c0, 0, 0, 0);
        c0 = __builtin_amdgcn_mfma_f32_32x32x16_bf16(wf2[1].v, hf[0][1].v, c0, 0, 0, 0);
        c1 = __builtin_amdgcn_mfma_f32_32x32x16_bf16(wf2[0].v, hf[1][0].v, c1, 0, 0, 0);
        c1 = __builtin_amdgcn_mfma_f32_32x32x16_bf16(wf2[1].v, hf[1][1].v, c1, 0, 0, 0);

        frag_u gf[2][2];
        #pragma unroll
        for (int t = 0; t < 2; ++t) {
            const f32x16 a = t ? c1 : c0;
            float h[16];
            #pragma unroll
            for (int r = 0; r < 16; ++r) h[r] = leaky(a[r]);
            gf[t][0].u[0] = cvt_pk(h[0], h[1]);   gf[t][0].u[1] = cvt_pk(h[2], h[3]);
            gf[t][0].u[2] = cvt_pk(h[4], h[5]);   gf[t][0].u[3] = cvt_pk(h[6], h[7]);
            gf[t][1].u[0] = cvt_pk(h[8], h[9]);   gf[t][1].u[1] = cvt_pk(h[10], h[11]);
            gf[t][1].u[2] = cvt_pk(h[12], h[13]); gf[t][1].u[3] = cvt_pk(h[14], h[15]);
        }

        f32x16 r0 = {}, r1 = {};
        r0 = __builtin_amdgcn_mfma_f32_32x32x16_bf16(wf3[0].v, gf[0][0].v, r0, 0, 0, 0);
        r0 = __builtin_amdgcn_mfma_f32_32x32x16_bf16(wf3[1].v, gf[0][1].v, r0, 0, 0, 0);
        r1 = __builtin_amdgcn_mfma_f32_32x32x16_bf16(wf3[0].v, gf[1][0].v, r1, 0, 0, 0);
        r1 = __builtin_amdgcn_mfma_f32_32x32x16_bf16(wf3[1].v, gf[1][1].v, r1, 0, 0, 0);

        #pragma unroll
        for (int t = 0; t < 2; ++t) {
            const f32x16 a = t ? r1 : r0;
            float* rr = &xrad[wv][32*t + m][0];
            *(float2*)&rr[4*g]          = make_float2(a[0],  a[1]);
            *(float2*)&rr[4*g + 2]      = make_float2(a[2],  a[3]);
            *(float2*)&rr[8 + 4*g]      = make_float2(a[4],  a[5]);
            *(float2*)&rr[8 + 4*g + 2]  = make_float2(a[6],  a[7]);
            *(float2*)&rr[16 + 4*g]     = make_float2(a[8],  a[9]);
            *(float2*)&rr[16 + 4*g + 2] = make_float2(a[10], a[11]);
            *(float2*)&rr[24 + 4*g]     = make_float2(a[12], a[13]);
            *(float2*)&rr[24 + 4*g + 2] = make_float2(a[14], a[15]);
        }
        wsync();

        #pragma unroll 4
        for (int l = 0; l < 64; ++l) {
            const float4 rvn = rvn_lds[wv][l];
            const int nd = __float_as_int(rvn.w);
            const float rd = xrad[wv][l][i];
            if (nd != cur) {
                if (cur >= 0) {
                    if (firstSeg) {
                        if (p == 0) {
                            atomicAdd(&A_a[cur*DA + i], accA);
                            atomicAdd(&out_v[(cur*DA + i)*3 + 0], a0);
                        } else {
                            atomicAdd(&out_v[(cur*DA + i)*3 + 1], a1);
                            atomicAdd(&out_v[(cur*DA + i)*3 + 2], a2);
                        }
                        firstSeg = false;
                    } else {
                        if (p == 0) {
                            A_a[cur*DA + i] = accA;
                            out_v[(cur*DA + i)*3 + 0] = a0;
                        } else {
                            out_v[(cur*DA + i)*3 + 1] = a1;
                            out_v[(cur*DA + i)*3 + 2] = a2;
                        }
                    }
                }
                accA = a0 = a1 = a2 = 0.0f;
                cur = nd;
            }
            accA += rd;
            a0 += rd * rvn.x;
            a1 += rd * rvn.y;
            a2 += rd * rvn.z;
        }
        wsync();
    }

    // final flush: may span forward across window boundary -> always atomic
    if (p == 0) {
        atomicAdd(&A_a[cur*DA + i], accA);
        atomicAdd(&out_v[(cur*DA + i)*3 + 0], a0);
    } else {
        atomicAdd(&out_v[(cur*DA + i)*3 + 1], a1);
        atomicAdd(&out_v[(cur*DA + i)*3 + 2], a2);
    }
}

// ---------------- phase B: out_v[n][v][d] = sum_a Wv[v][a] * A_v[n][a][d], in place ----------------

__global__ __launch_bounds__(256) void dt_node(
    const float* __restrict__ Wv,
    float* Av_out)   // aliased read+write, deliberately NOT restrict
{
    __shared__ float sWv[DA*DA];
    for (int i = threadIdx.x; i < DA*DA; i += 256) sWv[i] = Wv[i];
    __syncthreads();

    const int t = blockIdx.x * 256 + threadIdx.x;   // grid exactly NN*32/256
    const int n = t >> 5;
    const int v = t & 31;

    const float* av = Av_out + (size_t)n * (DA*3);
    float o0 = 0.0f, o1 = 0.0f, o2 = 0.0f;
    #pragma unroll
    for (int a = 0; a < DA; ++a) {
        const float w = sWv[v*DA + a];
        o0 += w * av[a*3 + 0];
        o1 += w * av[a*3 + 1];
        o2 += w * av[a*3 + 2];
    }
    __syncthreads();   // all loads of this block's nodes complete before any store
    float* o = Av_out + (size_t)n * (DA*3) + v*3;
    o[0] = o0; o[1] = o1; o[2] = o2;
}

// ---------------- legacy path (used only if ws too small for the new path) ----------------

__global__ __launch_bounds__(256) void k_hist_legacy(const int* __restrict__ src,
                                                     int* __restrict__ counts,
                                                     int* __restrict__ rank) {
    const int e = blockIdx.x * 256 + threadIdx.x;
    rank[e] = atomicAdd(&counts[src[e]], 1);
}

__global__ __launch_bounds__(256) void k_scan_legacy(const int* __restrict__ counts,
                                                     int* __restrict__ offsets) {
    __shared__ int part[256];
    const int CH = (NN + 255) / 256;
    const int t = threadIdx.x;
    const int base = t * CH;
    int s = 0;
    for (int k = 0; k < CH; ++k) { const int idx = base + k; if (idx < NN) s += counts[idx]; }
    part[t] = s;
    __syncthreads();
    if (t == 0) {
        int run = 0;
        for (int k = 0; k < 256; ++k) { const int v = part[k]; part[k] = run; run += v; }
    }
    __syncthreads();
    int run = part[t];
    for (int k = 0; k < CH; ++k) {
        const int idx = base + k;
        if (idx < NN) { offsets[idx] = run; run += counts[idx]; }
    }
    if (t == 255) offsets[NN] = run;
}

__global__ __launch_bounds__(256) void k_scatter_legacy(const int* __restrict__ src,
                                                        const int* __restrict__ offsets,
                                                        const int* __restrict__ rank,
                                                        int* __restrict__ edge_ids) {
    const int e = blockIdx.x * 256 + threadIdx.x;
    edge_ids[offsets[src[e]] + rank[e]] = e;
}

__global__ __launch_bounds__(256, 2) void dt_window_legacy(
    const float* __restrict__ r_ij,
    const float* __restrict__ res_emb,
    const int*   __restrict__ src,
    const int*   __restrict__ dst,
    const int*   __restrict__ edge_ids,
    const float* __restrict__ W1, const float* __restrict__ b1,
    const float* __restrict__ W2, const float* __restrict__ b2,
    const float* __restrict__ W3,
    float* __restrict__ A_a,
    float* __restrict__ out_v)
{
    __shared__ float  rad_lds[4][32][36];
    __shared__ float4 rvn_lds[4][64];

    const int tid  = threadIdx.x;
    const int wv   = tid >> 6;
    const int lane = tid & 63;
    const int slot = blockIdx.x * 256 + tid;

    const int eid  = edge_ids[slot];
    const int node = src[eid];

    const float rx = r_ij[(size_t)eid*3 + 0];
    const float ry = r_ij[(size_t)eid*3 + 1];
    const float rz = r_ij[(size_t)eid*3 + 2];
    const float dist = sqrtf(rx*rx + ry*ry + rz*rz);

    float xa[DA], xb[DA];
    #pragma unroll
    for (int mm = 0; mm < 8; ++mm) {
        float sph, cph;
        __sincosf(PI_R0 * (float)(mm + 1) * dist, &sph, &cph);
        xa[2*mm] = cph; xa[2*mm+1] = cph;
        xa[16+2*mm] = sph; xa[16+2*mm+1] = sph;
    }
    const float4* er = (const float4*)(res_emb + (size_t)dst[eid] * DA);
    #pragma unroll
    for (int q = 0; q < 8; ++q) {
        const float4 v = er[q];
        xa[q*4+0] += v.x; xa[q*4+1] += v.y; xa[q*4+2] += v.z; xa[q*4+3] += v.w;
    }
    #pragma unroll
    for (int i = 0; i < DA; ++i) {
        float acc = b1[i];
        #pragma unroll
        for (int j = 0; j < DA; ++j) acc += W1[i*DA + j] * xa[j];
        xb[i] = (acc >= 0.0f) ? acc : 0.1f * acc;
    }
    #pragma unroll
    for (int i = 0; i < DA; ++i) {
        float acc = b2[i];
        #pragma unroll
        for (int j = 0; j < DA; ++j) acc += W2[i*DA + j] * xb[j];
        xa[i] = (acc >= 0.0f) ? acc : 0.1f * acc;
    }
    #pragma unroll
    for (int i = 0; i < DA; ++i) {
        float acc = 0.0f;
        #pragma unroll
        for (int j = 0; j < DA; ++j) acc += W3[i*DA + j] * xa[j];
        xb[i] = acc;
    }

    const float qx = rx*1.4f, qy = ry*1.4f, qz = rz*1.4f;
    const float nq = sqrtf(qx*qx + qy*qy + qz*qz);
    const float e2 = __expf(2.0f * nq);
    const float sc = (nq > 0.0f)
        ? (e2 - 1.0f) * __builtin_amdgcn_rcpf((e2 + 1.0f) * nq)
        : 0.0f;

    rvn_lds[wv][lane] = make_float4(qx*sc, qy*sc, qz*sc, __int_as_float(node));

    const int p = lane >> 5;
    const int i = lane & 31;

    if (lane < 32) {
        float* rrow = rad_lds[wv][lane];
        #pragma unroll
        for (int q = 0; q < 8; ++q)
            *(float4*)&rrow[q*4] = make_float4(xb[q*4+0], xb[q*4+1], xb[q*4+2], xb[q*4+3]);
    }
    wsync();

    float accA = 0.0f, a0 = 0.0f, a1 = 0.0f, a2 = 0.0f;
    int cur = __float_as_int(rvn_lds[wv][0].w);

    #pragma unroll 4
    for (int l = 0; l < 32; ++l) {
        const float4 rvn = rvn_lds[wv][l];
        const int nd = __float_as_int(rvn.w);
        const float rd = rad_lds[wv][l][i];
        if (nd != cur) {
            if (p == 0) {
                atomicAdd(&A_a[cur*DA + i], accA);
                atomicAdd(&out_v[(cur*DA + i)*3 + 0], a0);
            } else {
                atomicAdd(&out_v[(cur*DA + i)*3 + 1], a1);
                atomicAdd(&out_v[(cur*DA + i)*3 + 2], a2);
            }
            accA = a0 = a1 = a2 = 0.0f;
            cur = nd;
        }
        accA += rd; a0 += rd*rvn.x; a1 += rd*rvn.y; a2 += rd*rvn.z;
    }
    wsync();
    if (lane >= 32) {
        float* rrow = rad_lds[wv][lane - 32];
        #pragma unroll
        for (int q = 0; q < 8; ++q)
            *(float4*)&rrow[q*4] = make_float4(xb[q*4+0], xb[q*4+1], xb[q*4+2], xb[q*4+3]);
    }
    wsync();
    #pragma unroll 4
    for (int l = 32; l < 64; ++l) {
        const float4 rvn = rvn_lds[wv][l];
        const int nd = __float_as_int(rvn.w);
        const float rd = rad_lds[wv][l - 32][i];
        if (nd != cur) {
            if (p == 0) {
                atomicAdd(&A_a[cur*DA + i], accA);
                atomicAdd(&out_v[(cur*DA + i)*3 + 0], a0);
            } else {
                atomicAdd(&out_v[(cur*DA + i)*3 + 1], a1);
                atomicAdd(&out_v[(cur*DA + i)*3 + 2], a2);
            }
            accA = a0 = a1 = a2 = 0.0f;
            cur = nd;
        }
        accA += rd; a0 += rd*rvn.x; a1 += rd*rvn.y; a2 += rd*rvn.z;
    }
    if (p == 0) {
        atomicAdd(&A_a[cur*DA + i], accA);
        atomicAdd(&out_v[(cur*DA + i)*3 + 0], a0);
    } else {
        atomicAdd(&out_v[(cur*DA + i)*3 + 1], a1);
        atomicAdd(&out_v[(cur*DA + i)*3 + 2], a2);
    }
}

// ---------------- launch ----------------

extern "C" void kernel_launch(void* const* d_in, const int* in_sizes, int n_in,
                              void* d_out, int out_size, void* d_ws, size_t ws_size,
                              hipStream_t stream) {
    const float* r_ij    = (const float*)d_in[0];
    const float* res_emb = (const float*)d_in[1];
    const int*   src     = (const int*)d_in[2];
    const int*   dst     = (const int*)d_in[3];
    const float* W1      = (const float*)d_in[4];
    const float* b1      = (const float*)d_in[5];
    const float* W2      = (const float*)d_in[6];
    const float* b2      = (const float*)d_in[7];
    const float* W3      = (const float*)d_in[8];
    const float* Wv      = (const float*)d_in[9];

    float* A_a   = (float*)d_out;                    // [NN][32]
    float* out_v = (float*)d_out + (size_t)NN * DA;  // [NN][32][3]

    // new-path ws: rec[NE*4] | emb16[NN*16] | counts[NB] | offsets[NB] | rank[NE] | bsum[256]
    const size_t need_new = ((size_t)NE*4 + (size_t)NN*16 + NB + NB + NE + 256) * sizeof(int);
    const size_t need_leg = ((size_t)NN + NN + 1 + NE + NE) * sizeof(int);

    if (ws_size >= need_new) {
        uint4*    rec     = (uint4*)d_ws;
        unsigned* emb16   = (unsigned*)(rec + NE);
        int*      counts  = (int*)(emb16 + (size_t)NN*16);   // [NB], 16B-aligned
        int*      offsets = counts + NB;                     // [NB], 16B-aligned
        int*      rank    = offsets + NB;
        int*      bsum    = rank + NE;

        k_init    <<<1024, 256, 0, stream>>>((uint4*)d_out, (uint4*)counts);
        k_hist_emb<<<HIST_BLOCKS + EMB_BLOCKS, 256, 0, stream>>>(src, counts, rank, res_emb, emb16);
        k_scanA   <<<SCAN_BLOCKS, 256, 0, stream>>>((const uint4*)counts, bsum);
        k_scanC   <<<SCAN_BLOCKS, 256, 0, stream>>>((const uint4*)counts, bsum, (uint4*)offsets);
        k_prep    <<<NE / 256, 256, 0, stream>>>(r_ij, src, dst, offsets, rank, rec);
        dt_window <<<NE / 512, 256, 0, stream>>>(rec, emb16, W1, b1, W2, b2, W3, A_a, out_v);
        dt_node   <<<(NN * DA) / 256, 256, 0, stream>>>(Wv, out_v);
    } else if (ws_size >= need_leg) {
        int* counts   = (int*)d_ws;
        int* offsets  = counts + NN;
        int* rank     = offsets + NN + 1;
        int* edge_ids = rank + NE;

        hipMemsetAsync(d_out, 0, (size_t)out_size * sizeof(float), stream);
        hipMemsetAsync(counts, 0, (size_t)NN * sizeof(int), stream);
        k_hist_legacy   <<<NE / 256, 256, 0, stream>>>(src, counts, rank);
        k_scan_legacy   <<<1, 256, 0, stream>>>(counts, offsets);
        k_scatter_legacy<<<NE / 256, 256, 0, stream>>>(src, offsets, rank, edge_ids);
        dt_window_legacy<<<NE / 256, 256, 0, stream>>>(r_ij, res_emb, src, dst, edge_ids,
                                                       W1, b1, W2, b2, W3, A_a, out_v);
        dt_node         <<<(NN * DA) / 256, 256, 0, stream>>>(Wv, out_v);
    }
}